// Round 9
// baseline (45061.942 us; speedup 1.0000x reference)
//
#include <hip/hip_runtime.h>
#include <hip/hip_fp16.h>

// Sizes fixed by the problem.
#define B_   64
#define T_   1024
#define H1_  128
#define H2_  256
#define TC_  256              // time-chunk for LSTM3/4
#define NCH  (T_ / TC_)       // 4 chunks
#define MCH  (B_ * TC_)       // 16384 rows per chunk per layer

typedef unsigned int  u32;
typedef unsigned short u16;
typedef _Float16 half2_t __attribute__((ext_vector_type(2)));

__device__ __forceinline__ float2 up2(u32 p) {
    __half2 h = __builtin_bit_cast(__half2, p);
    return __half22float2(h);
}
__device__ __forceinline__ u32 pk2(float a, float b) {
    __half2 h = __floats2half2_rn(a, b);
    return __builtin_bit_cast(u32, h);
}
__device__ __forceinline__ float hf(u16 u) { return __half2float(__builtin_bit_cast(__half, u)); }
__device__ __forceinline__ u16 fh(float f) { return __builtin_bit_cast(u16, __float2half(f)); }

// 2 MACs from packed fp16 pairs via fp32 FMA (compiler emits v_fma_mix — full
// rate, fp32 accumulate). Replaces fdot2 (r5-r8), which gave no speedup.
__device__ __forceinline__ float mac2(float acc, u32 wp_, u32 hp_) {
    half2_t w = __builtin_bit_cast(half2_t, wp_);
    half2_t h = __builtin_bit_cast(half2_t, hp_);
    acc = fmaf((float)w.x, (float)h.x, acc);
    return fmaf((float)w.y, (float)h.y, acc);
}

// fast gate nonlinearities: v_exp_f32 + v_rcp_f32 (~1e-7 rel err, overflow-safe)
__device__ __forceinline__ float sigf(float x) {
    return __builtin_amdgcn_rcpf(1.0f + __expf(-x));
}
__device__ __forceinline__ float tanhf_fast(float x) {
    float e = __expf(-2.0f * fabsf(x));
    float t = (1.0f - e) * __builtin_amdgcn_rcpf(1.0f + e);
    return __builtin_copysignf(t, x);
}

// Barrier that waits ONLY on LDS (lgkmcnt) — global loads/stores ride across.
__device__ __forceinline__ void barrier_lds_only() {
    asm volatile("s_waitcnt lgkmcnt(0)\n\ts_barrier" ::: "memory");
}

// ---------------------------------------------------------------------------
// Phase B: LSTM1 + LSTM2 (H=128). grid=128 (batch*2), block=512.
// SPLIT-K: thread (u, s) computes all 4 gates of unit u over K-range s;
// lane = s*16 + (u&15) -> 2x shfl_xor reduce, ONE lds-only barrier/step.
// MACs: scalar fma_mix on packed fp16 (r9: fdot2 removed).
// ---------------------------------------------------------------------------
__global__ __launch_bounds__(512) void lstm_small(
    const float* __restrict__ X, const float* __restrict__ cw, const float* __restrict__ cb,
    const float* __restrict__ Wi1, const float* __restrict__ Wh1, const float* __restrict__ b1,
    const float* __restrict__ Wi2, const float* __restrict__ Wh2, const float* __restrict__ b2,
    u16* __restrict__ x12)
{
    const int blk = blockIdx.x;
    const int b = blk >> 1;
    const int layer = blk & 1;
    const int j = threadIdx.x;
    const int s = (j >> 4) & 3;                 // K-quarter
    const int u = ((j >> 6) << 4) | (j & 15);   // unit 0..127

    const float* Wi = layer ? Wi2 : Wi1;
    const float* Wh = layer ? Wh2 : Wh1;
    const float* bb = layer ? b2 : b1;

    // conv fold (4 taps + bias) for the 4 gate columns of unit u
    float W4g[4][4], beff[4];
#pragma unroll
    for (int g = 0; g < 4; ++g) {
        const int col = g * 128 + u;
#pragma unroll
        for (int kk = 0; kk < 4; ++kk) {
            float sacc = 0.f;
#pragma unroll
            for (int c = 0; c < 16; ++c) {
                int cc = layer ? (15 - c) : c;
                sacc += cw[kk * 16 + c] * Wi[cc * 512 + col];
            }
            W4g[g][kk] = sacc;
        }
        float be = bb[col];
#pragma unroll
        for (int c = 0; c < 16; ++c) {
            int cc = layer ? (15 - c) : c;
            be += cb[c] * Wi[cc * 512 + col];
        }
        beff[g] = be;
    }

    // packed fp16 recurrent weights: gate g, pair p -> k2 = s*16+p
    u32 wreg[64];
#pragma unroll
    for (int g = 0; g < 4; ++g)
#pragma unroll
        for (int p = 0; p < 16; ++p) {
            int k2 = s * 16 + p;
            int col = g * 128 + u;
            wreg[g * 16 + p] = pk2(Wh[(2 * k2) * 512 + col], Wh[(2 * k2 + 1) * 512 + col]);
        }

    __shared__ __align__(16) u16 hb[2][4][40];   // 32 h + 8 pad per seg, dbuf
    if (s == 0) hb[0][u >> 5][u & 31] = 0;
    float c_state = 0.f;
    u16 hprev = 0;

    const float* Xb = X + (size_t)b * T_;
    float xm1 = 0.f, x0 = Xb[0], xp1 = Xb[1], xp2 = Xb[2];
    __syncthreads();

    int p = 0;
    for (int t = 0; t < T_; ++t) {
        if (s == 0 && t > 0)
            x12[((size_t)b * T_ + t - 1) * 256 + layer * 128 + u] = hprev;
        float xnext = (t + 3 < T_) ? Xb[t + 3] : 0.f;

        const uint4* hp4 = (const uint4*)&hb[p][s][0];
        float vz0 = 0.f, vz1 = 0.f, vz2 = 0.f, vz3 = 0.f;
#pragma unroll
        for (int m = 0; m < 4; ++m) {
            uint4 hh = hp4[m];
            u32 hw[4] = {hh.x, hh.y, hh.z, hh.w};
#pragma unroll
            for (int c = 0; c < 4; ++c) {
                int idx = 4 * m + c;
                vz0 = mac2(vz0, wreg[idx],      hw[c]);
                vz1 = mac2(vz1, wreg[16 + idx], hw[c]);
                vz2 = mac2(vz2, wreg[32 + idx], hw[c]);
                vz3 = mac2(vz3, wreg[48 + idx], hw[c]);
            }
        }
        vz0 += __shfl_xor(vz0, 16); vz0 += __shfl_xor(vz0, 32);
        vz1 += __shfl_xor(vz1, 16); vz1 += __shfl_xor(vz1, 32);
        vz2 += __shfl_xor(vz2, 16); vz2 += __shfl_xor(vz2, 32);
        vz3 += __shfl_xor(vz3, 16); vz3 += __shfl_xor(vz3, 32);

        float z0 = vz0 + beff[0] + xm1 * W4g[0][0] + x0 * W4g[0][1] + xp1 * W4g[0][2] + xp2 * W4g[0][3];
        float z1 = vz1 + beff[1] + xm1 * W4g[1][0] + x0 * W4g[1][1] + xp1 * W4g[1][2] + xp2 * W4g[1][3];
        float z2 = vz2 + beff[2] + xm1 * W4g[2][0] + x0 * W4g[2][1] + xp1 * W4g[2][2] + xp2 * W4g[2][3];
        float z3 = vz3 + beff[3] + xm1 * W4g[3][0] + x0 * W4g[3][1] + xp1 * W4g[3][2] + xp2 * W4g[3][3];

        float gi = sigf(z0), gf = sigf(z1), gg = tanhf_fast(z2), go = sigf(z3);
        c_state = gf * c_state + gi * gg;
        float h = go * tanhf_fast(c_state);
        hprev = fh(h);
        if (s == 0) hb[p ^ 1][u >> 5][u & 31] = hprev;
        barrier_lds_only();
        p ^= 1;
        xm1 = x0; x0 = xp1; xp1 = xp2; xp2 = xnext;
    }
    if (s == 0)
        x12[((size_t)b * T_ + T_ - 1) * 256 + layer * 128 + u] = hprev;
}

// ---------------------------------------------------------------------------
// Wh3/Wh4 (256 x 1024 fp32) -> packed fp16 pairs, layout [l][k2][j]:
//   wpk[l*131072 + k2*1024 + j] = half(Wh[2k2][j]) | half(Wh[2k2+1][j])<<16
// ---------------------------------------------------------------------------
__global__ void cvt_wh(const float* __restrict__ Wh3, const float* __restrict__ Wh4,
                       u32* __restrict__ wpk)
{
    int idx = blockIdx.x * 256 + threadIdx.x;   // < 262144
    int l = idx >> 17;
    int rem = idx & 131071;
    int k2 = rem >> 10;
    int j = rem & 1023;
    const float* W = l ? Wh4 : Wh3;
    wpk[idx] = pk2(W[(2 * k2) * 1024 + j], W[(2 * k2 + 1) * 1024 + j]);
}

// ---------------------------------------------------------------------------
// Tiled GEMM, 128x128 tile, 256 threads, 8x8/thread, K-tile 16. A is fp16.
// KREV: reverse B's K index (feature flip). CHUNK: A-row remap for time chunks.
// OUTMODE 0: out fp16 (acc+bias)    OUTMODE 1: out fp32 tanh(acc+bias)
// ---------------------------------------------------------------------------
template<int KREV, int OUTMODE, int CHUNK>
__global__ __launch_bounds__(256) void gemm128(
    const u16* __restrict__ A, const float* __restrict__ Bm,
    const float* __restrict__ bias, void* __restrict__ outv,
    int t0, int N, int K)
{
    __shared__ __align__(16) float Alds[16][132];
    __shared__ __align__(16) float Blds[16][128];
    const int tid = threadIdx.x;
    const int m0 = blockIdx.x * 128;
    const int n0 = blockIdx.y * 128;
    const int tm = tid >> 4, tn = tid & 15;
    const int ar = tid >> 1, ak = (tid & 1) * 8;
    const int bk = tid >> 4, bn = (tid & 15) * 8;

    int arow = m0 + ar;
    if (CHUNK) arow = (arow >> 8) * T_ + t0 + (arow & 255);

    float acc[8][8];
#pragma unroll
    for (int r = 0; r < 8; ++r)
#pragma unroll
        for (int c = 0; c < 8; ++c) acc[r][c] = 0.f;

    for (int k0 = 0; k0 < K; k0 += 16) {
        const u16* Ap = A + (size_t)arow * K + k0 + ak;
        uint4 u = *(const uint4*)Ap;
        float2 f0 = up2(u.x), f1 = up2(u.y), f2 = up2(u.z), f3 = up2(u.w);
        float av[8] = {f0.x, f0.y, f1.x, f1.y, f2.x, f2.y, f3.x, f3.y};

        int krow = KREV ? (K - 1 - (k0 + bk)) : (k0 + bk);
        const float* Bp = Bm + (size_t)krow * N + n0 + bn;
        float4 bv0 = *(const float4*)Bp;
        float4 bv1 = *(const float4*)(Bp + 4);
#pragma unroll
        for (int i = 0; i < 8; ++i) Alds[ak + i][ar] = av[i];
        *(float4*)&Blds[bk][bn] = bv0;
        *(float4*)&Blds[bk][bn + 4] = bv1;
        __syncthreads();
#pragma unroll
        for (int kk = 0; kk < 16; ++kk) {
            float a[8], bb8[8];
            *(float4*)a         = *(const float4*)&Alds[kk][tm * 8];
            *(float4*)(a + 4)   = *(const float4*)&Alds[kk][tm * 8 + 4];
            *(float4*)bb8       = *(const float4*)&Blds[kk][tn * 8];
            *(float4*)(bb8 + 4) = *(const float4*)&Blds[kk][tn * 8 + 4];
#pragma unroll
            for (int r = 0; r < 8; ++r)
#pragma unroll
                for (int c = 0; c < 8; ++c) acc[r][c] += a[r] * bb8[c];
        }
        __syncthreads();
    }

    float bv[8];
#pragma unroll
    for (int c = 0; c < 8; ++c) bv[c] = bias[n0 + tn * 8 + c];

    if (OUTMODE == 0) {
        u16* outp = (u16*)outv;
#pragma unroll
        for (int r = 0; r < 8; ++r) {
            u32 pk[4];
#pragma unroll
            for (int c2 = 0; c2 < 4; ++c2)
                pk[c2] = pk2(acc[r][2 * c2] + bv[2 * c2], acc[r][2 * c2 + 1] + bv[2 * c2 + 1]);
            uint4 st = make_uint4(pk[0], pk[1], pk[2], pk[3]);
            *(uint4*)(outp + (size_t)(m0 + tm * 8 + r) * N + n0 + tn * 8) = st;
        }
    } else {
        float* outp = (float*)outv;
#pragma unroll
        for (int r = 0; r < 8; ++r) {
            float v[8];
#pragma unroll
            for (int c = 0; c < 8; ++c) v[c] = tanhf(acc[r][c] + bv[c]);
            *(float4*)(outp + (size_t)(m0 + tm * 8 + r) * N + n0 + tn * 8)     = *(float4*)v;
            *(float4*)(outp + (size_t)(m0 + tm * 8 + r) * N + n0 + tn * 8 + 4) = *(float4*)(v + 4);
        }
    }
}

// ---------------------------------------------------------------------------
// Phase C: LSTM3 + LSTM4 (H=256) over one time chunk [t0, t0+TC_).
// grid=128, block=512. SPLIT-K 2-way: thread (u in [0,256), s in {0,1}),
// lane bit5 = s -> one shfl_xor(32) reduce, ONE lds-only barrier/step.
// Weights: 256 packed pairs/thread total. Gates i,f,g (192 pairs) in VGPRs —
// amdgpu_waves_per_eu(2,2) caps occupancy at 2 waves/SIMD giving a 256-VGPR
// budget (r8 post-mortem: default allocator capped at 64 and spilled ALL
// weights to scratch -> vmem-bound at ~8800 cy/step). Gate o (64 pairs) in
// LDS as [q4][j] uint4 (conflict-free ds_read_b128). MACs via fma_mix.
// ---------------------------------------------------------------------------
__global__ __attribute__((amdgpu_flat_work_group_size(512, 512), amdgpu_waves_per_eu(2, 2)))
void lstm_big(
    const u16* __restrict__ pre, const u32* __restrict__ wpk,
    float* __restrict__ state, u16* __restrict__ enc, int t0)
{
    const int blk = blockIdx.x;
    const int b = blk >> 1;
    const int layer = blk & 1;
    const int j = threadIdx.x;
    const int s = (j >> 5) & 1;                 // K-half (lane bit 5)
    const int u = ((j >> 6) << 5) | (j & 31);   // unit 0..255

    __shared__ __align__(16) uint4 wl4[16 * 512];   // o-gate weights, 128 KB
    __shared__ __align__(16) u32 hb[2][136];        // 256 h packed + pad, dbuf

    const u32* wp = wpk + (size_t)layer * 131072;   // [k2][1024] packed pairs
    // gates i,f,g: 64 pairs each in VGPRs (k2 = s*64 + p)
    u32 wreg[192];
#pragma unroll
    for (int g = 0; g < 3; ++g)
#pragma unroll
        for (int p = 0; p < 64; ++p)
            wreg[g * 64 + p] = wp[(s * 64 + p) * 1024 + g * 256 + u];
    // gate o: 64 pairs into LDS, self-owned slot, uint4-packed
#pragma unroll
    for (int q4 = 0; q4 < 16; ++q4) {
        uint4 v;
        v.x = wp[(s * 64 + 4 * q4 + 0) * 1024 + 768 + u];
        v.y = wp[(s * 64 + 4 * q4 + 1) * 1024 + 768 + u];
        v.z = wp[(s * 64 + 4 * q4 + 2) * 1024 + 768 + u];
        v.w = wp[(s * 64 + 4 * q4 + 3) * 1024 + 768 + u];
        wl4[q4 * 512 + j] = v;
    }

    float* st = state + ((size_t)layer * B_ + b) * 512;
    float c_state = (t0 == 0) ? 0.f : st[u];
    float h0      = (t0 == 0) ? 0.f : st[256 + u];
    u16* hb16 = (u16*)&hb[0][0];
    if (s == 0) hb16[u] = fh(h0);

    const u16* pbase = pre + (size_t)(layer * MCH + b * TC_) * 1024;
    u16 c0 = pbase[u], c1 = pbase[256 + u], c2 = pbase[512 + u], c3 = pbase[768 + u];
    __syncthreads();

    u16 hprev = 0;
    float h_lastf = h0;
    int p = 0;
    for (int tt = 0; tt < TC_; ++tt) {
        if (s == 0 && tt > 0)
            enc[((size_t)b * T_ + t0 + tt - 1) * 512 + layer * 256 + u] = hprev;
        // prefetch next step's gate inputs
        const u16* pn = pbase + (size_t)(tt + 1) * 1024;
        u16 n0 = 0, n1 = 0, n2 = 0, n3 = 0;
        if (tt + 1 < TC_) { n0 = pn[u]; n1 = pn[256 + u]; n2 = pn[512 + u]; n3 = pn[768 + u]; }

        const uint4* hbase = (const uint4*)&hb[p][s * 64];
        float vz0 = 0.f, vz1 = 0.f, vz2 = 0.f, vz3 = 0.f;
#pragma unroll
        for (int q = 0; q < 16; ++q) {
            uint4 hh = hbase[q];
            uint4 wo = wl4[q * 512 + j];
            u32 hw[4] = {hh.x, hh.y, hh.z, hh.w};
            u32 ww[4] = {wo.x, wo.y, wo.z, wo.w};
#pragma unroll
            for (int c = 0; c < 4; ++c) {
                const int idx = q * 4 + c;
                vz0 = mac2(vz0, wreg[idx],       hw[c]);
                vz1 = mac2(vz1, wreg[64 + idx],  hw[c]);
                vz2 = mac2(vz2, wreg[128 + idx], hw[c]);
                vz3 = mac2(vz3, ww[c],           hw[c]);
            }
        }
        vz0 += __shfl_xor(vz0, 32);
        vz1 += __shfl_xor(vz1, 32);
        vz2 += __shfl_xor(vz2, 32);
        vz3 += __shfl_xor(vz3, 32);

        float gi = sigf(vz0 + hf(c0)), gf = sigf(vz1 + hf(c1));
        float gg = tanhf_fast(vz2 + hf(c2)), go = sigf(vz3 + hf(c3));
        c_state = gf * c_state + gi * gg;
        float h = go * tanhf_fast(c_state);
        h_lastf = h;
        hprev = fh(h);
        if (s == 0) ((u16*)&hb[p ^ 1][0])[u] = hprev;
        barrier_lds_only();
        p ^= 1;
        c0 = n0; c1 = n1; c2 = n2; c3 = n3;
    }
    if (s == 0) {
        enc[((size_t)b * T_ + t0 + TC_ - 1) * 512 + layer * 256 + u] = hprev;
        st[u] = c_state;
        st[256 + u] = h_lastf;
    }
}

// ---------------------------------------------------------------------------
// Attention pooling + head, one workgroup per batch.
// ---------------------------------------------------------------------------
__global__ __launch_bounds__(256) void attn_head(
    const float* __restrict__ S1, const u16* __restrict__ enc,
    const float* __restrict__ attV, const float* __restrict__ attVb,
    const float* __restrict__ d1W, const float* __restrict__ d1b,
    const float* __restrict__ d2W, const float* __restrict__ d2b,
    float* __restrict__ out)
{
    const int b = blockIdx.x;
    const int tid = threadIdx.x;
    const int lane = tid & 63, w = tid >> 6;

    __shared__ float sb[1024];
    __shared__ float red[32];
    __shared__ __align__(16) float ctx[512];
    __shared__ float h1s[128];

    float av0 = attV[lane], av1 = attV[64 + lane];
    const float* S1b = S1 + (size_t)b * T_ * 128;
    for (int it = 0; it < 256; ++it) {
        int t = it * 4 + w;
        const float* row = S1b + (size_t)t * 128;
        float p = row[lane] * av0 + row[64 + lane] * av1;
#pragma unroll
        for (int off = 32; off > 0; off >>= 1) p += __shfl_down(p, off);
        if (lane == 0) sb[t] = p + attVb[0];
    }
    __syncthreads();

    float mx = -3.0e38f;
#pragma unroll
    for (int q = 0; q < 4; ++q) mx = fmaxf(mx, sb[tid + 256 * q]);
#pragma unroll
    for (int off = 32; off > 0; off >>= 1) mx = fmaxf(mx, __shfl_down(mx, off));
    if (lane == 0) red[w] = mx;
    __syncthreads();
    if (tid == 0) red[8] = fmaxf(fmaxf(red[0], red[1]), fmaxf(red[2], red[3]));
    __syncthreads();
    float bm = red[8];
    float s = 0.f;
#pragma unroll
    for (int q = 0; q < 4; ++q) {
        float e = expf(sb[tid + 256 * q] - bm);
        sb[tid + 256 * q] = e;
        s += e;
    }
#pragma unroll
    for (int off = 32; off > 0; off >>= 1) s += __shfl_down(s, off);
    if (lane == 0) red[16 + w] = s;
    __syncthreads();
    if (tid == 0) red[24] = 1.0f / (red[16] + red[17] + red[18] + red[19]);
    __syncthreads();
    float inv = red[24];
#pragma unroll
    for (int q = 0; q < 4; ++q) sb[tid + 256 * q] *= inv;
    __syncthreads();

    const u16* encb = enc + (size_t)b * T_ * 512;
    float a0 = 0.f, a1 = 0.f;
    for (int t = 0; t < T_; ++t) {
        float wt = sb[t];
        a0 += wt * hf(encb[(size_t)t * 512 + tid]);
        a1 += wt * hf(encb[(size_t)t * 512 + 256 + tid]);
    }
    ctx[tid] = a0;
    ctx[256 + tid] = a1;
    __syncthreads();

    if (tid < 128) {
        float s1 = d1b[tid];
        for (int k = 0; k < 512; ++k) s1 += ctx[k] * d1W[k * 128 + tid];
        h1s[tid] = tanhf(s1);
    }
    __syncthreads();
    if (tid < 128) {
        float p = h1s[tid] * d2W[tid];
#pragma unroll
        for (int off = 32; off > 0; off >>= 1) p += __shfl_down(p, off);
        if ((tid & 63) == 0) red[28 + (tid >> 6)] = p;
    }
    __syncthreads();
    if (tid == 0) out[b] = red[28] + red[29] + d2b[0];
}

// ---------------------------------------------------------------------------
extern "C" void kernel_launch(void* const* d_in, const int* in_sizes, int n_in,
                              void* d_out, int out_size, void* d_ws, size_t ws_size,
                              hipStream_t stream)
{
    const float* X    = (const float*)d_in[0];
    const float* cw   = (const float*)d_in[1];
    const float* cb   = (const float*)d_in[2];
    const float* Wi1  = (const float*)d_in[3];
    const float* Wh1  = (const float*)d_in[4];
    const float* b1   = (const float*)d_in[5];
    const float* Wi2  = (const float*)d_in[6];
    const float* Wh2  = (const float*)d_in[7];
    const float* b2   = (const float*)d_in[8];
    const float* Wi3  = (const float*)d_in[9];
    const float* Wh3  = (const float*)d_in[10];
    const float* b3   = (const float*)d_in[11];
    const float* Wi4  = (const float*)d_in[12];
    const float* Wh4  = (const float*)d_in[13];
    const float* b4   = (const float*)d_in[14];
    const float* attW = (const float*)d_in[15];
    const float* attWb= (const float*)d_in[16];
    const float* attV = (const float*)d_in[17];
    const float* attVb= (const float*)d_in[18];
    const float* d1W  = (const float*)d_in[19];
    const float* d1b  = (const float*)d_in[20];
    const float* d2W  = (const float*)d_in[21];
    const float* d2b  = (const float*)d_in[22];
    float* out = (float*)d_out;

    // workspace layout (total 169,082,880 B ~ 161.3 MiB):
    char* w = (char*)d_ws;
    u16*   x12  = (u16*)w;                          // 64*1024*256*2      = 33,554,432
    u16*   pre  = (u16*)(w + 33554432);             // 2*16384*1024*2     = 67,108,864 (per chunk)
    u16*   enc  = (u16*)(w + 100663296);            // 64*1024*512*2      = 67,108,864
    u32*   wpk  = (u32*)(w + 167772160);            // 2*128*1024*4       =  1,048,576
    float* state= (float*)(w + 168820736);          // 2*64*512*4         =    262,144
    float* S1   = (float*)(w + 33554432);           // 65536*128*4 = 32 MiB, aliases pre (dead)

    lstm_small<<<128, 512, 0, stream>>>(X, cw, cb, Wi1, Wh1, b1, Wi2, Wh2, b2, x12);
    cvt_wh<<<1024, 256, 0, stream>>>(Wh3, Wh4, wpk);

    for (int c = 0; c < NCH; ++c) {
        int t0 = c * TC_;
        gemm128<0, 0, 1><<<dim3(128, 8), 256, 0, stream>>>(x12, Wi3, b3, pre, t0, 1024, 256);
        gemm128<1, 0, 1><<<dim3(128, 8), 256, 0, stream>>>(x12, Wi4, b4, pre + (size_t)MCH * 1024, t0, 1024, 256);
        lstm_big<<<128, 512, 0, stream>>>(pre, wpk, state, enc, t0);
    }

    gemm128<0, 1, 0><<<dim3(512, 1), 256, 0, stream>>>(enc, attW, attWb, S1, 0, 128, 512);
    attn_head<<<64, 256, 0, stream>>>(S1, enc, attV, attVb, d1W, d1b, d2W, d2b, out);
}

// Round 10
// 4047.381 us; speedup vs baseline: 11.1336x; 11.1336x over previous
//
#include <hip/hip_runtime.h>
#include <hip/hip_fp16.h>

// Sizes fixed by the problem.
#define B_   64
#define T_   1024
#define H1_  128
#define H2_  256
#define TC_  128              // time-chunk for LSTM3/4
#define NCH  (T_ / TC_)       // 8 chunks
#define MCH  (B_ * TC_)       // 8192 rows per chunk per layer

#define WREG 92               // lstm_big: packed weight pairs in VGPRs per thread
#define WLDS 36               // lstm_big: packed weight pairs in LDS per thread

typedef unsigned int  u32;
typedef unsigned short u16;
typedef _Float16 half2_t __attribute__((ext_vector_type(2)));

__device__ __forceinline__ float fdot2(u32 w, u32 h, float acc) {
    // v_dot2_f32_f16: acc += w.lo*h.lo + w.hi*h.hi (fp32 accumulate)
    return __builtin_amdgcn_fdot2(__builtin_bit_cast(half2_t, w),
                                  __builtin_bit_cast(half2_t, h), acc, false);
}
__device__ __forceinline__ u32 pk2(float a, float b) {
    __half2 h = __floats2half2_rn(a, b);
    return __builtin_bit_cast(u32, h);
}
__device__ __forceinline__ float hf(u16 u) { return __half2float(__builtin_bit_cast(__half, u)); }
__device__ __forceinline__ u16 fh(float f) { return __builtin_bit_cast(u16, __float2half(f)); }
__device__ __forceinline__ float sigf(float x) { return 1.0f / (1.0f + expf(-x)); }

// ---------------------------------------------------------------------------
// Phase B: LSTM1 + LSTM2 (H=128). grid=128 (batch*2), block=512 (1 gate col).
// Wh packed fp16 in 64 VGPRs/thread; h packed fp16 in LDS; fdot2 inner loop.
// Own-gate nonlinearity before the exchange; 2 barriers/step. (= round-4 file,
// the best-measured configuration: 700-737 us.)
// ---------------------------------------------------------------------------
__global__ __launch_bounds__(512) void lstm_small(
    const float* __restrict__ X, const float* __restrict__ cw, const float* __restrict__ cb,
    const float* __restrict__ Wi1, const float* __restrict__ Wh1, const float* __restrict__ b1,
    const float* __restrict__ Wi2, const float* __restrict__ Wh2, const float* __restrict__ b2,
    u16* __restrict__ x12)
{
    const int blk = blockIdx.x;
    const int b = blk >> 1;
    const int layer = blk & 1;
    const int j = threadIdx.x;

    const float* Wi = layer ? Wi2 : Wi1;
    const float* Wh = layer ? Wh2 : Wh1;
    const float* bb = layer ? b2 : b1;

    // fold conv into 4 taps + bias
    float W4[4];
#pragma unroll
    for (int kk = 0; kk < 4; ++kk) {
        float s = 0.f;
#pragma unroll
        for (int c = 0; c < 16; ++c) {
            int cc = layer ? (15 - c) : c;
            s += cw[kk * 16 + c] * Wi[cc * 512 + j];
        }
        W4[kk] = s;
    }
    float beff = bb[j];
#pragma unroll
    for (int c = 0; c < 16; ++c) {
        int cc = layer ? (15 - c) : c;
        beff += cb[c] * Wi[cc * 512 + j];
    }

    // packed fp16 recurrent weights: pair p = (Wh[2p][j], Wh[2p+1][j])
    u32 whp[64];
#pragma unroll
    for (int p = 0; p < 64; ++p)
        whp[p] = pk2(Wh[(2 * p) * 512 + j], Wh[(2 * p + 1) * 512 + j]);

    __shared__ __align__(16) u32 hbuf_pk[64];   // 128 h as packed fp16
    __shared__ float zbuf[512];
    u16* hb16 = (u16*)hbuf_pk;
    if (j < 128) hb16[j] = 0;
    float c_state = 0.f;

    const float* Xb = X + (size_t)b * T_;
    float xm1 = 0.f, x0 = Xb[0], xp1 = Xb[1], xp2 = Xb[2];
    __syncthreads();

    const uint4* hp4 = (const uint4*)hbuf_pk;
    for (int t = 0; t < T_; ++t) {
        float xnext = (t + 3 < T_) ? Xb[t + 3] : 0.f;

        float za = beff + xm1 * W4[0] + x0 * W4[1] + xp1 * W4[2] + xp2 * W4[3];
        float zb = 0.f, zc = 0.f, zd = 0.f;
#pragma unroll
        for (int m = 0; m < 16; ++m) {
            uint4 hh = hp4[m];
            za = fdot2(whp[4 * m + 0], hh.x, za);
            zb = fdot2(whp[4 * m + 1], hh.y, zb);
            zc = fdot2(whp[4 * m + 2], hh.z, zc);
            zd = fdot2(whp[4 * m + 3], hh.w, zd);
        }
        float z = (za + zb) + (zc + zd);
        // own-gate nonlinearity (wave-uniform branch): g-gate is [256,384)
        zbuf[j] = (j >= 256 && j < 384) ? tanhf(z) : sigf(z);
        __syncthreads();
        if (j < 128) {
            float gi = zbuf[j], gf = zbuf[128 + j], gg = zbuf[256 + j], go = zbuf[384 + j];
            c_state = gf * c_state + gi * gg;
            float h = go * tanhf(c_state);
            hb16[j] = fh(h);
            x12[((size_t)b * T_ + t) * 256 + layer * 128 + j] = fh(h);
        }
        xm1 = x0; x0 = xp1; xp1 = xp2; xp2 = xnext;
        __syncthreads();
    }
}

// ---------------------------------------------------------------------------
// Weight conversions to packed fp16 pairs:
//  wpk  [2][128][1024]: Wh3/Wh4 pairs (k2, col j)
//  wi3pk[128][1024]:    Wi3 pairs
//  wi4pk[128][1024]:    Wi4 pairs with the feature-flip baked in (rows 255-2k2, 254-2k2)
//  awpk [256][128]:     attW pairs
// ---------------------------------------------------------------------------
__global__ void cvt_all(const float* __restrict__ Wh3, const float* __restrict__ Wh4,
                        const float* __restrict__ Wi3, const float* __restrict__ Wi4,
                        const float* __restrict__ attW,
                        u32* __restrict__ wpk, u32* __restrict__ wi3pk,
                        u32* __restrict__ wi4pk, u32* __restrict__ awpk)
{
    int idx = blockIdx.x * 256 + threadIdx.x;   // < 557056
    if (idx < 262144) {
        int l = idx >> 17, rem = idx & 131071, k2 = rem >> 10, j = rem & 1023;
        const float* W = l ? Wh4 : Wh3;
        wpk[idx] = pk2(W[(2 * k2) * 1024 + j], W[(2 * k2 + 1) * 1024 + j]);
    } else if (idx < 393216) {
        int rel = idx - 262144, k2 = rel >> 10, n = rel & 1023;
        wi3pk[rel] = pk2(Wi3[(2 * k2) * 1024 + n], Wi3[(2 * k2 + 1) * 1024 + n]);
    } else if (idx < 524288) {
        int rel = idx - 393216, k2 = rel >> 10, n = rel & 1023;
        wi4pk[rel] = pk2(Wi4[(255 - 2 * k2) * 1024 + n], Wi4[(254 - 2 * k2) * 1024 + n]);
    } else if (idx < 557056) {
        int rel = idx - 524288, k2 = rel >> 7, n = rel & 127;
        awpk[rel] = pk2(attW[(2 * k2) * 128 + n], attW[(2 * k2 + 1) * 128 + n]);
    }
}

// ---------------------------------------------------------------------------
// Packed-fp16 GEMM via v_dot2_f32_f16: 128x128 tile, 256 threads, 8x8/thread,
// K-tile 16 (8 packed pairs). A fp16 (u16), B packed pairs (u32 [K/2][N]).
// 512 fdot2/tile vs 1024 fma in the fp32 version; LDS traffic halved.
// CHUNK: A-row remap chunk-local -> global time rows.
// OUTMODE 0: out fp16 (acc+bias)    OUTMODE 1: out fp32 tanh(acc+bias)
// ---------------------------------------------------------------------------
template<int OUTMODE, int CHUNK>
__global__ __launch_bounds__(256) void gemm128pk(
    const u16* __restrict__ A, const u32* __restrict__ Bpk,
    const float* __restrict__ bias, void* __restrict__ outv,
    int t0, int N, int K)
{
    __shared__ __align__(16) u32 Apk[8][132];
    __shared__ __align__(16) u32 Bld[8][128];
    const int tid = threadIdx.x;
    const int m0 = blockIdx.x * 128;
    const int n0 = blockIdx.y * 128;
    const int tm = tid >> 4, tn = tid & 15;
    const int ar = tid >> 1, ap = (tid & 1) * 4;    // A row, A pair offset
    const int bkp = tid >> 5, bn4 = (tid & 31) * 4; // B pair row, B col

    int arow = m0 + ar;
    if (CHUNK) arow = (arow >> 7) * T_ + t0 + (arow & (TC_ - 1));

    float acc[8][8];
#pragma unroll
    for (int r = 0; r < 8; ++r)
#pragma unroll
        for (int c = 0; c < 8; ++c) acc[r][c] = 0.f;

    for (int k0 = 0; k0 < K; k0 += 16) {
        uint4 ua = *(const uint4*)(A + (size_t)arow * K + k0 + ap * 2);      // 8 fp16 = 4 pairs
        uint4 ub = *(const uint4*)(Bpk + (size_t)((k0 >> 1) + bkp) * N + n0 + bn4);
        Apk[ap + 0][ar] = ua.x; Apk[ap + 1][ar] = ua.y;
        Apk[ap + 2][ar] = ua.z; Apk[ap + 3][ar] = ua.w;
        *(uint4*)&Bld[bkp][bn4] = ub;
        __syncthreads();
#pragma unroll
        for (int kp = 0; kp < 8; ++kp) {
            u32 a[8], bp[8];
            *(uint4*)(a)      = *(const uint4*)&Apk[kp][tm * 8];
            *(uint4*)(a + 4)  = *(const uint4*)&Apk[kp][tm * 8 + 4];
            *(uint4*)(bp)     = *(const uint4*)&Bld[kp][tn * 8];
            *(uint4*)(bp + 4) = *(const uint4*)&Bld[kp][tn * 8 + 4];
#pragma unroll
            for (int r = 0; r < 8; ++r)
#pragma unroll
                for (int c = 0; c < 8; ++c)
                    acc[r][c] = fdot2(a[r], bp[c], acc[r][c]);
        }
        __syncthreads();
    }

    float bv[8];
#pragma unroll
    for (int c = 0; c < 8; ++c) bv[c] = bias[n0 + tn * 8 + c];

    if (OUTMODE == 0) {
        u16* outp = (u16*)outv;
#pragma unroll
        for (int r = 0; r < 8; ++r) {
            u32 pkv[4];
#pragma unroll
            for (int c2 = 0; c2 < 4; ++c2)
                pkv[c2] = pk2(acc[r][2 * c2] + bv[2 * c2], acc[r][2 * c2 + 1] + bv[2 * c2 + 1]);
            uint4 st = make_uint4(pkv[0], pkv[1], pkv[2], pkv[3]);
            *(uint4*)(outp + (size_t)(m0 + tm * 8 + r) * N + n0 + tn * 8) = st;
        }
    } else {
        float* outp = (float*)outv;
#pragma unroll
        for (int r = 0; r < 8; ++r) {
            float v[8];
#pragma unroll
            for (int c = 0; c < 8; ++c) v[c] = tanhf(acc[r][c] + bv[c]);
            *(float4*)(outp + (size_t)(m0 + tm * 8 + r) * N + n0 + tn * 8)     = *(float4*)v;
            *(float4*)(outp + (size_t)(m0 + tm * 8 + r) * N + n0 + tn * 8 + 4) = *(float4*)(v + 4);
        }
    }
}

// ---------------------------------------------------------------------------
// Phase C: LSTM3 + LSTM4 (H=256) over one time chunk [t0, t0+TC_).
// grid=128 (batch*2), block=1024: thread j owns gate column j (of 1024).
// WREG=92 packed fp16 pairs in VGPRs + WLDS=36 in LDS per thread; h packed
// fp16 in LDS; own-gate nonlinearity; 2 barriers/step. (= round-4 file.)
// ---------------------------------------------------------------------------
__global__ __launch_bounds__(1024) void lstm_big(
    const u16* __restrict__ pre, const u32* __restrict__ wpk,
    float* __restrict__ state, u16* __restrict__ enc, int t0)
{
    const int blk = blockIdx.x;
    const int b = blk >> 1;
    const int layer = blk & 1;
    const int j = threadIdx.x;

    __shared__ u32 wlds[WLDS * 1024];           // 147456 B, uint2 pairs [q2][1024]
    __shared__ __align__(16) u32 hbuf_pk[128];  // 256 h as packed fp16
    __shared__ float zbuf[1024];

    const u32* wp = wpk + (size_t)layer * 131072;  // [k2][1024] packed fp16 pairs
    u32 wreg[WREG];
#pragma unroll
    for (int q = 0; q < WREG; ++q) wreg[q] = wp[q * 1024 + j];
    uint2* wl = (uint2*)wlds;
#pragma unroll
    for (int q2 = 0; q2 < WLDS / 2; ++q2)
        wl[q2 * 1024 + j] = make_uint2(wp[(WREG + 2 * q2) * 1024 + j],
                                       (WREG + 2 * q2 + 1 < 128) ? wp[(WREG + 2 * q2 + 1) * 1024 + j] : 0u);

    float* st = state + ((size_t)layer * B_ + b) * 512;
    u16* hb16 = (u16*)hbuf_pk;
    float c_state = 0.f, h_last = 0.f;
    if (j < 256) {
        float h0 = (t0 == 0) ? 0.f : st[256 + j];
        c_state = (t0 == 0) ? 0.f : st[j];
        hb16[j] = fh(h0);
        h_last = h0;
    }
    __syncthreads();

    const u16* prow = pre + (size_t)(layer * MCH + b * TC_) * 1024;
    u16* encrow = enc + ((size_t)b * T_ + t0) * 512 + layer * 256;
    const uint4* hp4 = (const uint4*)hbuf_pk;

    for (int tt = 0; tt < TC_; ++tt, prow += 1024, encrow += 512) {
        float za = hf(prow[j]), zb = 0.f, zc = 0.f, zd = 0.f;
#pragma unroll
        for (int m = 0; m < WREG / 4; ++m) {       // pairs 0..91 from registers
            uint4 hh = hp4[m];
            za = fdot2(wreg[4 * m + 0], hh.x, za);
            zb = fdot2(wreg[4 * m + 1], hh.y, zb);
            zc = fdot2(wreg[4 * m + 2], hh.z, zc);
            zd = fdot2(wreg[4 * m + 3], hh.w, zd);
        }
#pragma unroll
        for (int m = 0; m < WLDS / 4; ++m) {       // pairs 92..127 from LDS
            uint4 hh = hp4[WREG / 4 + m];
            uint2 w0 = wl[(2 * m + 0) * 1024 + j];
            uint2 w1 = wl[(2 * m + 1) * 1024 + j];
            za = fdot2(w0.x, hh.x, za);
            zb = fdot2(w0.y, hh.y, zb);
            zc = fdot2(w1.x, hh.z, zc);
            zd = fdot2(w1.y, hh.w, zd);
        }
        float z = (za + zb) + (zc + zd);
        // own-gate nonlinearity, wave-uniform branch: g-gate is [512,768)
        zbuf[j] = (j >= 512 && j < 768) ? tanhf(z) : sigf(z);
        __syncthreads();
        if (j < 256) {
            float gi = zbuf[j], gf = zbuf[256 + j], gg = zbuf[512 + j], go = zbuf[768 + j];
            c_state = gf * c_state + gi * gg;
            float h = go * tanhf(c_state);
            hb16[j] = fh(h);
            encrow[j] = fh(h);
            h_last = h;
        }
        __syncthreads();
    }
    if (j < 256) { st[j] = c_state; st[256 + j] = h_last; }
}

// ---------------------------------------------------------------------------
// Attention pooling + head, one workgroup per batch.
// ---------------------------------------------------------------------------
__global__ __launch_bounds__(256) void attn_head(
    const float* __restrict__ S1, const u16* __restrict__ enc,
    const float* __restrict__ attV, const float* __restrict__ attVb,
    const float* __restrict__ d1W, const float* __restrict__ d1b,
    const float* __restrict__ d2W, const float* __restrict__ d2b,
    float* __restrict__ out)
{
    const int b = blockIdx.x;
    const int tid = threadIdx.x;
    const int lane = tid & 63, w = tid >> 6;

    __shared__ float sb[1024];
    __shared__ float red[32];
    __shared__ __align__(16) float ctx[512];
    __shared__ float h1s[128];

    float av0 = attV[lane], av1 = attV[64 + lane];
    const float* S1b = S1 + (size_t)b * T_ * 128;
    for (int it = 0; it < 256; ++it) {
        int t = it * 4 + w;
        const float* row = S1b + (size_t)t * 128;
        float p = row[lane] * av0 + row[64 + lane] * av1;
#pragma unroll
        for (int off = 32; off > 0; off >>= 1) p += __shfl_down(p, off);
        if (lane == 0) sb[t] = p + attVb[0];
    }
    __syncthreads();

    float mx = -3.0e38f;
#pragma unroll
    for (int q = 0; q < 4; ++q) mx = fmaxf(mx, sb[tid + 256 * q]);
#pragma unroll
    for (int off = 32; off > 0; off >>= 1) mx = fmaxf(mx, __shfl_down(mx, off));
    if (lane == 0) red[w] = mx;
    __syncthreads();
    if (tid == 0) red[8] = fmaxf(fmaxf(red[0], red[1]), fmaxf(red[2], red[3]));
    __syncthreads();
    float bm = red[8];
    float s = 0.f;
#pragma unroll
    for (int q = 0; q < 4; ++q) {
        float e = expf(sb[tid + 256 * q] - bm);
        sb[tid + 256 * q] = e;
        s += e;
    }
#pragma unroll
    for (int off = 32; off > 0; off >>= 1) s += __shfl_down(s, off);
    if (lane == 0) red[16 + w] = s;
    __syncthreads();
    if (tid == 0) red[24] = 1.0f / (red[16] + red[17] + red[18] + red[19]);
    __syncthreads();
    float inv = red[24];
#pragma unroll
    for (int q = 0; q < 4; ++q) sb[tid + 256 * q] *= inv;
    __syncthreads();

    const u16* encb = enc + (size_t)b * T_ * 512;
    float a0 = 0.f, a1 = 0.f;
    for (int t = 0; t < T_; ++t) {
        float wt = sb[t];
        a0 += wt * hf(encb[(size_t)t * 512 + tid]);
        a1 += wt * hf(encb[(size_t)t * 512 + 256 + tid]);
    }
    ctx[tid] = a0;
    ctx[256 + tid] = a1;
    __syncthreads();

    if (tid < 128) {
        float s1 = d1b[tid];
        for (int k = 0; k < 512; ++k) s1 += ctx[k] * d1W[k * 128 + tid];
        h1s[tid] = tanhf(s1);
    }
    __syncthreads();
    if (tid < 128) {
        float p = h1s[tid] * d2W[tid];
#pragma unroll
        for (int off = 32; off > 0; off >>= 1) p += __shfl_down(p, off);
        if ((tid & 63) == 0) red[28 + (tid >> 6)] = p;
    }
    __syncthreads();
    if (tid == 0) out[b] = red[28] + red[29] + d2b[0];
}

// ---------------------------------------------------------------------------
extern "C" void kernel_launch(void* const* d_in, const int* in_sizes, int n_in,
                              void* d_out, int out_size, void* d_ws, size_t ws_size,
                              hipStream_t stream)
{
    const float* X    = (const float*)d_in[0];
    const float* cw   = (const float*)d_in[1];
    const float* cb   = (const float*)d_in[2];
    const float* Wi1  = (const float*)d_in[3];
    const float* Wh1  = (const float*)d_in[4];
    const float* b1   = (const float*)d_in[5];
    const float* Wi2  = (const float*)d_in[6];
    const float* Wh2  = (const float*)d_in[7];
    const float* b2   = (const float*)d_in[8];
    const float* Wi3  = (const float*)d_in[9];
    const float* Wh3  = (const float*)d_in[10];
    const float* b3   = (const float*)d_in[11];
    const float* Wi4  = (const float*)d_in[12];
    const float* Wh4  = (const float*)d_in[13];
    const float* b4   = (const float*)d_in[14];
    const float* attW = (const float*)d_in[15];
    const float* attWb= (const float*)d_in[16];
    const float* attV = (const float*)d_in[17];
    const float* attVb= (const float*)d_in[18];
    const float* d1W  = (const float*)d_in[19];
    const float* d1b  = (const float*)d_in[20];
    const float* d2W  = (const float*)d_in[21];
    const float* d2b  = (const float*)d_in[22];
    float* out = (float*)d_out;

    // workspace layout (total 136,708,096 B ~ 130.4 MiB — under r2's proven 169 MB):
    char* w = (char*)d_ws;
    u16*   x12  = (u16*)w;                          // 64*1024*256*2    = 33,554,432
    u16*   pre  = (u16*)(w + 33554432);             // 2*8192*1024*2    = 33,554,432 (per chunk)
    u16*   enc  = (u16*)(w + 67108864);             // 64*1024*512*2    = 67,108,864
    u32*   wpk  = (u32*)(w + 134217728);            // 2*128*1024*4     =  1,048,576
    float* state= (float*)(w + 135266304);          // 2*64*512*4       =    262,144
    u32*   wi3pk= (u32*)(w + 135528448);            // 128*1024*4       =    524,288
    u32*   wi4pk= (u32*)(w + 136052736);            // 128*1024*4       =    524,288
    u32*   awpk = (u32*)(w + 136577024);            // 256*128*4        =    131,072
    float* S1   = (float*)(w + 33554432);           // 65536*128*4 = 32 MiB, aliases pre (dead)

    lstm_small<<<128, 512, 0, stream>>>(X, cw, cb, Wi1, Wh1, b1, Wi2, Wh2, b2, x12);
    cvt_all<<<2176, 256, 0, stream>>>(Wh3, Wh4, Wi3, Wi4, attW, wpk, wi3pk, wi4pk, awpk);

    for (int c = 0; c < NCH; ++c) {
        int t0 = c * TC_;
        gemm128pk<0, 1><<<dim3(64, 8), 256, 0, stream>>>(x12, wi3pk, b3, pre, t0, 1024, 256);
        gemm128pk<0, 1><<<dim3(64, 8), 256, 0, stream>>>(x12, wi4pk, b4, pre + (size_t)MCH * 1024, t0, 1024, 256);
        lstm_big<<<128, 1024, 0, stream>>>(pre, wpk, state, enc, t0);
    }

    gemm128pk<1, 0><<<dim3(512, 1), 256, 0, stream>>>(enc, awpk, attWb, S1, 0, 128, 512);
    attn_head<<<64, 256, 0, stream>>>(S1, enc, attV, attVb, d1W, d1b, d2W, d2b, out);
}

// Round 11
// 3314.402 us; speedup vs baseline: 13.5958x; 1.2211x over previous
//
#include <hip/hip_runtime.h>
#include <hip/hip_fp16.h>

// Sizes fixed by the problem.
#define B_   64
#define T_   1024
#define H1_  128
#define H2_  256
#define TC_  128              // time-chunk for LSTM3/4
#define NCH  (T_ / TC_)       // 8 chunks
#define MCH  (B_ * TC_)       // 8192 rows per chunk per layer

typedef unsigned int  u32;
typedef unsigned short u16;
typedef _Float16 half2_t __attribute__((ext_vector_type(2)));

__device__ __forceinline__ float fdot2(u32 w, u32 h, float acc) {
    // v_dot2_f32_f16: acc += w.lo*h.lo + w.hi*h.hi (fp32 accumulate)
    return __builtin_amdgcn_fdot2(__builtin_bit_cast(half2_t, w),
                                  __builtin_bit_cast(half2_t, h), acc, false);
}
__device__ __forceinline__ u32 pk2(float a, float b) {
    __half2 h = __floats2half2_rn(a, b);
    return __builtin_bit_cast(u32, h);
}
__device__ __forceinline__ float hf(u16 u) { return __half2float(__builtin_bit_cast(__half, u)); }
__device__ __forceinline__ u16 fh(float f) { return __builtin_bit_cast(u16, __float2half(f)); }
__device__ __forceinline__ float sigf(float x) { return 1.0f / (1.0f + expf(-x)); }

// ---------------------------------------------------------------------------
// Phase B: LSTM1 + LSTM2 (H=128). grid=128 (batch*2), block=512 (1 gate col).
// Wh packed fp16 in 64 VGPRs/thread (proven resident: VGPR_Count=80); h packed
// fp16 in LDS; fdot2 inner loop; own-gate nonlinearity; 2 barriers/step.
// (= round-4/round-10 file, best-measured: ~720 us.)
// ---------------------------------------------------------------------------
__global__ __launch_bounds__(512) void lstm_small(
    const float* __restrict__ X, const float* __restrict__ cw, const float* __restrict__ cb,
    const float* __restrict__ Wi1, const float* __restrict__ Wh1, const float* __restrict__ b1,
    const float* __restrict__ Wi2, const float* __restrict__ Wh2, const float* __restrict__ b2,
    u16* __restrict__ x12)
{
    const int blk = blockIdx.x;
    const int b = blk >> 1;
    const int layer = blk & 1;
    const int j = threadIdx.x;

    const float* Wi = layer ? Wi2 : Wi1;
    const float* Wh = layer ? Wh2 : Wh1;
    const float* bb = layer ? b2 : b1;

    // fold conv into 4 taps + bias
    float W4[4];
#pragma unroll
    for (int kk = 0; kk < 4; ++kk) {
        float s = 0.f;
#pragma unroll
        for (int c = 0; c < 16; ++c) {
            int cc = layer ? (15 - c) : c;
            s += cw[kk * 16 + c] * Wi[cc * 512 + j];
        }
        W4[kk] = s;
    }
    float beff = bb[j];
#pragma unroll
    for (int c = 0; c < 16; ++c) {
        int cc = layer ? (15 - c) : c;
        beff += cb[c] * Wi[cc * 512 + j];
    }

    // packed fp16 recurrent weights: pair p = (Wh[2p][j], Wh[2p+1][j])
    u32 whp[64];
#pragma unroll
    for (int p = 0; p < 64; ++p)
        whp[p] = pk2(Wh[(2 * p) * 512 + j], Wh[(2 * p + 1) * 512 + j]);

    __shared__ __align__(16) u32 hbuf_pk[64];   // 128 h as packed fp16
    __shared__ float zbuf[512];
    u16* hb16 = (u16*)hbuf_pk;
    if (j < 128) hb16[j] = 0;
    float c_state = 0.f;

    const float* Xb = X + (size_t)b * T_;
    float xm1 = 0.f, x0 = Xb[0], xp1 = Xb[1], xp2 = Xb[2];
    __syncthreads();

    const uint4* hp4 = (const uint4*)hbuf_pk;
    for (int t = 0; t < T_; ++t) {
        float xnext = (t + 3 < T_) ? Xb[t + 3] : 0.f;

        float za = beff + xm1 * W4[0] + x0 * W4[1] + xp1 * W4[2] + xp2 * W4[3];
        float zb = 0.f, zc = 0.f, zd = 0.f;
#pragma unroll
        for (int m = 0; m < 16; ++m) {
            uint4 hh = hp4[m];
            za = fdot2(whp[4 * m + 0], hh.x, za);
            zb = fdot2(whp[4 * m + 1], hh.y, zb);
            zc = fdot2(whp[4 * m + 2], hh.z, zc);
            zd = fdot2(whp[4 * m + 3], hh.w, zd);
        }
        float z = (za + zb) + (zc + zd);
        // own-gate nonlinearity (wave-uniform branch): g-gate is [256,384)
        zbuf[j] = (j >= 256 && j < 384) ? tanhf(z) : sigf(z);
        __syncthreads();
        if (j < 128) {
            float gi = zbuf[j], gf = zbuf[128 + j], gg = zbuf[256 + j], go = zbuf[384 + j];
            c_state = gf * c_state + gi * gg;
            float h = go * tanhf(c_state);
            hb16[j] = fh(h);
            x12[((size_t)b * T_ + t) * 256 + layer * 128 + j] = fh(h);
        }
        xm1 = x0; x0 = xp1; xp1 = xp2; xp2 = xnext;
        __syncthreads();
    }
}

// ---------------------------------------------------------------------------
// Weight conversions to packed fp16 pairs:
//  wpk  [2][128][1024]: Wh3/Wh4 pairs (k2, col j)
//  wi3pk[128][1024]:    Wi3 pairs
//  wi4pk[128][1024]:    Wi4 pairs with the feature-flip baked in
//  awpk [256][128]:     attW pairs
//  wpkT [2][14][1024]:  Wh3/Wh4 pairs k2=72..127 as uint4 chunks (4 k2/chunk),
//                       lane-contiguous for coalesced per-step streaming
// ---------------------------------------------------------------------------
__global__ void cvt_all(const float* __restrict__ Wh3, const float* __restrict__ Wh4,
                        const float* __restrict__ Wi3, const float* __restrict__ Wi4,
                        const float* __restrict__ attW,
                        u32* __restrict__ wpk, u32* __restrict__ wi3pk,
                        u32* __restrict__ wi4pk, u32* __restrict__ awpk,
                        uint4* __restrict__ wpkT)
{
    int idx = blockIdx.x * 256 + threadIdx.x;   // < 585728
    if (idx < 262144) {
        int l = idx >> 17, rem = idx & 131071, k2 = rem >> 10, j = rem & 1023;
        const float* W = l ? Wh4 : Wh3;
        wpk[idx] = pk2(W[(2 * k2) * 1024 + j], W[(2 * k2 + 1) * 1024 + j]);
    } else if (idx < 393216) {
        int rel = idx - 262144, k2 = rel >> 10, n = rel & 1023;
        wi3pk[rel] = pk2(Wi3[(2 * k2) * 1024 + n], Wi3[(2 * k2 + 1) * 1024 + n]);
    } else if (idx < 524288) {
        int rel = idx - 393216, k2 = rel >> 10, n = rel & 1023;
        wi4pk[rel] = pk2(Wi4[(255 - 2 * k2) * 1024 + n], Wi4[(254 - 2 * k2) * 1024 + n]);
    } else if (idx < 557056) {
        int rel = idx - 524288, k2 = rel >> 7, n = rel & 127;
        awpk[rel] = pk2(attW[(2 * k2) * 128 + n], attW[(2 * k2 + 1) * 128 + n]);
    } else if (idx < 585728) {
        int rel = idx - 557056;          // < 28672 = 2 * 14 * 1024
        int l = rel / 14336;
        int rem = rel - l * 14336;
        int q = rem >> 10, col = rem & 1023;
        const float* W = l ? Wh4 : Wh3;
        int k2 = 72 + 4 * q;
        uint4 v;
        v.x = pk2(W[(2 * k2 + 0) * 1024 + col], W[(2 * k2 + 1) * 1024 + col]);
        v.y = pk2(W[(2 * k2 + 2) * 1024 + col], W[(2 * k2 + 3) * 1024 + col]);
        v.z = pk2(W[(2 * k2 + 4) * 1024 + col], W[(2 * k2 + 5) * 1024 + col]);
        v.w = pk2(W[(2 * k2 + 6) * 1024 + col], W[(2 * k2 + 7) * 1024 + col]);
        wpkT[rel] = v;
    }
}

// ---------------------------------------------------------------------------
// Packed-fp16 GEMM via v_dot2_f32_f16: 128x128 tile, 256 threads, 8x8/thread,
// K-tile 16 (8 packed pairs). A fp16 (u16), B packed pairs (u32 [K/2][N]).
// CHUNK: A-row remap chunk-local -> global time rows.
// OUTMODE 0: out fp16 (acc+bias)    OUTMODE 1: out fp32 tanh(acc+bias)
// ---------------------------------------------------------------------------
template<int OUTMODE, int CHUNK>
__global__ __launch_bounds__(256) void gemm128pk(
    const u16* __restrict__ A, const u32* __restrict__ Bpk,
    const float* __restrict__ bias, void* __restrict__ outv,
    int t0, int N, int K)
{
    __shared__ __align__(16) u32 Apk[8][132];
    __shared__ __align__(16) u32 Bld[8][128];
    const int tid = threadIdx.x;
    const int m0 = blockIdx.x * 128;
    const int n0 = blockIdx.y * 128;
    const int tm = tid >> 4, tn = tid & 15;
    const int ar = tid >> 1, ap = (tid & 1) * 4;    // A row, A pair offset
    const int bkp = tid >> 5, bn4 = (tid & 31) * 4; // B pair row, B col

    int arow = m0 + ar;
    if (CHUNK) arow = (arow >> 7) * T_ + t0 + (arow & (TC_ - 1));

    float acc[8][8];
#pragma unroll
    for (int r = 0; r < 8; ++r)
#pragma unroll
        for (int c = 0; c < 8; ++c) acc[r][c] = 0.f;

    for (int k0 = 0; k0 < K; k0 += 16) {
        uint4 ua = *(const uint4*)(A + (size_t)arow * K + k0 + ap * 2);      // 8 fp16 = 4 pairs
        uint4 ub = *(const uint4*)(Bpk + (size_t)((k0 >> 1) + bkp) * N + n0 + bn4);
        Apk[ap + 0][ar] = ua.x; Apk[ap + 1][ar] = ua.y;
        Apk[ap + 2][ar] = ua.z; Apk[ap + 3][ar] = ua.w;
        *(uint4*)&Bld[bkp][bn4] = ub;
        __syncthreads();
#pragma unroll
        for (int kp = 0; kp < 8; ++kp) {
            u32 a[8], bp[8];
            *(uint4*)(a)      = *(const uint4*)&Apk[kp][tm * 8];
            *(uint4*)(a + 4)  = *(const uint4*)&Apk[kp][tm * 8 + 4];
            *(uint4*)(bp)     = *(const uint4*)&Bld[kp][tn * 8];
            *(uint4*)(bp + 4) = *(const uint4*)&Bld[kp][tn * 8 + 4];
#pragma unroll
            for (int r = 0; r < 8; ++r)
#pragma unroll
                for (int c = 0; c < 8; ++c)
                    acc[r][c] = fdot2(a[r], bp[c], acc[r][c]);
        }
        __syncthreads();
    }

    float bv[8];
#pragma unroll
    for (int c = 0; c < 8; ++c) bv[c] = bias[n0 + tn * 8 + c];

    if (OUTMODE == 0) {
        u16* outp = (u16*)outv;
#pragma unroll
        for (int r = 0; r < 8; ++r) {
            u32 pkv[4];
#pragma unroll
            for (int c2 = 0; c2 < 4; ++c2)
                pkv[c2] = pk2(acc[r][2 * c2] + bv[2 * c2], acc[r][2 * c2 + 1] + bv[2 * c2 + 1]);
            uint4 st = make_uint4(pkv[0], pkv[1], pkv[2], pkv[3]);
            *(uint4*)(outp + (size_t)(m0 + tm * 8 + r) * N + n0 + tn * 8) = st;
        }
    } else {
        float* outp = (float*)outv;
#pragma unroll
        for (int r = 0; r < 8; ++r) {
            float v[8];
#pragma unroll
            for (int c = 0; c < 8; ++c) v[c] = tanhf(acc[r][c] + bv[c]);
            *(float4*)(outp + (size_t)(m0 + tm * 8 + r) * N + n0 + tn * 8)     = *(float4*)v;
            *(float4*)(outp + (size_t)(m0 + tm * 8 + r) * N + n0 + tn * 8 + 4) = *(float4*)(v + 4);
        }
    }
}

// ---------------------------------------------------------------------------
// Phase C: LSTM3 + LSTM4 (H=256) over one time chunk [t0, t0+TC_).
// grid=128 (batch*2), block=512: thread j owns gate columns j and 512+j.
// Weight residency plan per column (128 packed pairs):
//   k2  0..35  -> VGPR  (36/col, 72/thread; +temps ~120 < 128-cap => resident)
//   k2 36..71  -> LDS   (147 KB, uint4 conflict-free)
//   k2 72..127 -> streamed per step from wpkT (coalesced uint4, L2-resident,
//                 shared across the 64 blocks of the layer)
// Streaming model: 229 KB/step @ ~56 B/cy/CU => ~1.7 us/step (was ~2.7 with
// only 36/128 resident via scratch spill — r4..r10 post-mortems).
// ---------------------------------------------------------------------------
__global__ __launch_bounds__(512) void lstm_big(
    const u16* __restrict__ pre, const u32* __restrict__ wpk,
    const uint4* __restrict__ wpkT,
    float* __restrict__ state, u16* __restrict__ enc, int t0)
{
    const int blk = blockIdx.x;
    const int b = blk >> 1;
    const int layer = blk & 1;
    const int j = threadIdx.x;          // 0..511

    __shared__ __align__(16) uint4 wlA[9][512];   // col j,     pairs k2 36..71
    __shared__ __align__(16) uint4 wlB[9][512];   // col 512+j, pairs k2 36..71
    __shared__ __align__(16) u32 hbuf_pk[128];    // 256 h packed fp16
    __shared__ float zbuf[1024];

    const u32* wp = wpk + (size_t)layer * 131072;   // [k2][1024]
    u32 wrA[36], wrB[36];
#pragma unroll
    for (int q = 0; q < 36; ++q) {
        wrA[q] = wp[q * 1024 + j];
        wrB[q] = wp[q * 1024 + 512 + j];
    }
#pragma unroll
    for (int m = 0; m < 9; ++m) {
        uint4 va, vb;
        va.x = wp[(36 + 4 * m + 0) * 1024 + j];
        va.y = wp[(36 + 4 * m + 1) * 1024 + j];
        va.z = wp[(36 + 4 * m + 2) * 1024 + j];
        va.w = wp[(36 + 4 * m + 3) * 1024 + j];
        vb.x = wp[(36 + 4 * m + 0) * 1024 + 512 + j];
        vb.y = wp[(36 + 4 * m + 1) * 1024 + 512 + j];
        vb.z = wp[(36 + 4 * m + 2) * 1024 + 512 + j];
        vb.w = wp[(36 + 4 * m + 3) * 1024 + 512 + j];
        wlA[m][j] = va;
        wlB[m][j] = vb;
    }
    const uint4* wt = wpkT + (size_t)layer * 14 * 1024;   // [q][col] chunks

    float* st = state + ((size_t)layer * B_ + b) * 512;
    u16* hb16 = (u16*)hbuf_pk;
    float c_state = 0.f, h_last = 0.f;
    if (j < 256) {
        float h0 = (t0 == 0) ? 0.f : st[256 + j];
        c_state = (t0 == 0) ? 0.f : st[j];
        hb16[j] = fh(h0);
        h_last = h0;
    }
    __syncthreads();

    const u16* prow = pre + (size_t)(layer * MCH + b * TC_) * 1024;
    u16* encrow = enc + ((size_t)b * T_ + t0) * 512 + layer * 256;
    const uint4* hp4 = (const uint4*)hbuf_pk;

    for (int tt = 0; tt < TC_; ++tt, prow += 1024, encrow += 512) {
        u16 pA = prow[j], pB = prow[512 + j];
        float a0 = 0.f, a1 = 0.f, b0 = 0.f, b1 = 0.f;
#pragma unroll
        for (int m = 0; m < 9; ++m) {           // pairs 0..35 from VGPR
            uint4 hh = hp4[m];
            a0 = fdot2(wrA[4 * m + 0], hh.x, a0);
            a1 = fdot2(wrA[4 * m + 1], hh.y, a1);
            a0 = fdot2(wrA[4 * m + 2], hh.z, a0);
            a1 = fdot2(wrA[4 * m + 3], hh.w, a1);
            b0 = fdot2(wrB[4 * m + 0], hh.x, b0);
            b1 = fdot2(wrB[4 * m + 1], hh.y, b1);
            b0 = fdot2(wrB[4 * m + 2], hh.z, b0);
            b1 = fdot2(wrB[4 * m + 3], hh.w, b1);
        }
#pragma unroll
        for (int m = 0; m < 9; ++m) {           // pairs 36..71 from LDS
            uint4 hh = hp4[9 + m];
            uint4 wa = wlA[m][j];
            uint4 wb = wlB[m][j];
            a0 = fdot2(wa.x, hh.x, a0); a1 = fdot2(wa.y, hh.y, a1);
            a0 = fdot2(wa.z, hh.z, a0); a1 = fdot2(wa.w, hh.w, a1);
            b0 = fdot2(wb.x, hh.x, b0); b1 = fdot2(wb.y, hh.y, b1);
            b0 = fdot2(wb.z, hh.z, b0); b1 = fdot2(wb.w, hh.w, b1);
        }
#pragma unroll
        for (int q = 0; q < 14; ++q) {          // pairs 72..127 streamed (L2)
            uint4 hh = hp4[18 + q];
            uint4 wa = wt[q * 1024 + j];
            uint4 wb = wt[q * 1024 + 512 + j];
            a0 = fdot2(wa.x, hh.x, a0); a1 = fdot2(wa.y, hh.y, a1);
            a0 = fdot2(wa.z, hh.z, a0); a1 = fdot2(wa.w, hh.w, a1);
            b0 = fdot2(wb.x, hh.x, b0); b1 = fdot2(wb.y, hh.y, b1);
            b0 = fdot2(wb.z, hh.z, b0); b1 = fdot2(wb.w, hh.w, b1);
        }
        float zA = (a0 + a1) + hf(pA);          // col j: gate i (j<256) or f
        float zB = (b0 + b1) + hf(pB);          // col 512+j: gate g or o
        zbuf[j] = sigf(zA);
        zbuf[512 + j] = (j < 256) ? tanhf(zB) : sigf(zB);   // wave-uniform split
        __syncthreads();
        if (j < 256) {
            float gi = zbuf[j], gf = zbuf[256 + j], gg = zbuf[512 + j], go = zbuf[768 + j];
            c_state = gf * c_state + gi * gg;
            float h = go * tanhf(c_state);
            hb16[j] = fh(h);
            encrow[j] = fh(h);
            h_last = h;
        }
        __syncthreads();
    }
    if (j < 256) { st[j] = c_state; st[256 + j] = h_last; }
}

// ---------------------------------------------------------------------------
// Attention pooling + head, one workgroup per batch.
// ---------------------------------------------------------------------------
__global__ __launch_bounds__(256) void attn_head(
    const float* __restrict__ S1, const u16* __restrict__ enc,
    const float* __restrict__ attV, const float* __restrict__ attVb,
    const float* __restrict__ d1W, const float* __restrict__ d1b,
    const float* __restrict__ d2W, const float* __restrict__ d2b,
    float* __restrict__ out)
{
    const int b = blockIdx.x;
    const int tid = threadIdx.x;
    const int lane = tid & 63, w = tid >> 6;

    __shared__ float sb[1024];
    __shared__ float red[32];
    __shared__ __align__(16) float ctx[512];
    __shared__ float h1s[128];

    float av0 = attV[lane], av1 = attV[64 + lane];
    const float* S1b = S1 + (size_t)b * T_ * 128;
    for (int it = 0; it < 256; ++it) {
        int t = it * 4 + w;
        const float* row = S1b + (size_t)t * 128;
        float p = row[lane] * av0 + row[64 + lane] * av1;
#pragma unroll
        for (int off = 32; off > 0; off >>= 1) p += __shfl_down(p, off);
        if (lane == 0) sb[t] = p + attVb[0];
    }
    __syncthreads();

    float mx = -3.0e38f;
#pragma unroll
    for (int q = 0; q < 4; ++q) mx = fmaxf(mx, sb[tid + 256 * q]);
#pragma unroll
    for (int off = 32; off > 0; off >>= 1) mx = fmaxf(mx, __shfl_down(mx, off));
    if (lane == 0) red[w] = mx;
    __syncthreads();
    if (tid == 0) red[8] = fmaxf(fmaxf(red[0], red[1]), fmaxf(red[2], red[3]));
    __syncthreads();
    float bm = red[8];
    float s = 0.f;
#pragma unroll
    for (int q = 0; q < 4; ++q) {
        float e = expf(sb[tid + 256 * q] - bm);
        sb[tid + 256 * q] = e;
        s += e;
    }
#pragma unroll
    for (int off = 32; off > 0; off >>= 1) s += __shfl_down(s, off);
    if (lane == 0) red[16 + w] = s;
    __syncthreads();
    if (tid == 0) red[24] = 1.0f / (red[16] + red[17] + red[18] + red[19]);
    __syncthreads();
    float inv = red[24];
#pragma unroll
    for (int q = 0; q < 4; ++q) sb[tid + 256 * q] *= inv;
    __syncthreads();

    const u16* encb = enc + (size_t)b * T_ * 512;
    float a0 = 0.f, a1 = 0.f;
    for (int t = 0; t < T_; ++t) {
        float wt = sb[t];
        a0 += wt * hf(encb[(size_t)t * 512 + tid]);
        a1 += wt * hf(encb[(size_t)t * 512 + 256 + tid]);
    }
    ctx[tid] = a0;
    ctx[256 + tid] = a1;
    __syncthreads();

    if (tid < 128) {
        float s1 = d1b[tid];
        for (int k = 0; k < 512; ++k) s1 += ctx[k] * d1W[k * 128 + tid];
        h1s[tid] = tanhf(s1);
    }
    __syncthreads();
    if (tid < 128) {
        float p = h1s[tid] * d2W[tid];
#pragma unroll
        for (int off = 32; off > 0; off >>= 1) p += __shfl_down(p, off);
        if ((tid & 63) == 0) red[28 + (tid >> 6)] = p;
    }
    __syncthreads();
    if (tid == 0) out[b] = red[28] + red[29] + d2b[0];
}

// ---------------------------------------------------------------------------
extern "C" void kernel_launch(void* const* d_in, const int* in_sizes, int n_in,
                              void* d_out, int out_size, void* d_ws, size_t ws_size,
                              hipStream_t stream)
{
    const float* X    = (const float*)d_in[0];
    const float* cw   = (const float*)d_in[1];
    const float* cb   = (const float*)d_in[2];
    const float* Wi1  = (const float*)d_in[3];
    const float* Wh1  = (const float*)d_in[4];
    const float* b1   = (const float*)d_in[5];
    const float* Wi2  = (const float*)d_in[6];
    const float* Wh2  = (const float*)d_in[7];
    const float* b2   = (const float*)d_in[8];
    const float* Wi3  = (const float*)d_in[9];
    const float* Wh3  = (const float*)d_in[10];
    const float* b3   = (const float*)d_in[11];
    const float* Wi4  = (const float*)d_in[12];
    const float* Wh4  = (const float*)d_in[13];
    const float* b4   = (const float*)d_in[14];
    const float* attW = (const float*)d_in[15];
    const float* attWb= (const float*)d_in[16];
    const float* attV = (const float*)d_in[17];
    const float* attVb= (const float*)d_in[18];
    const float* d1W  = (const float*)d_in[19];
    const float* d1b  = (const float*)d_in[20];
    const float* d2W  = (const float*)d_in[21];
    const float* d2b  = (const float*)d_in[22];
    float* out = (float*)d_out;

    // workspace layout (total 137,166,848 B ~ 130.8 MiB — under r2's proven 169 MB):
    char* w = (char*)d_ws;
    u16*   x12  = (u16*)w;                          // 64*1024*256*2    = 33,554,432
    u16*   pre  = (u16*)(w + 33554432);             // 2*8192*1024*2    = 33,554,432 (per chunk)
    u16*   enc  = (u16*)(w + 67108864);             // 64*1024*512*2    = 67,108,864
    u32*   wpk  = (u32*)(w + 134217728);            // 2*128*1024*4     =  1,048,576
    float* state= (float*)(w + 135266304);          // 2*64*512*4       =    262,144
    u32*   wi3pk= (u32*)(w + 135528448);            // 128*1024*4       =    524,288
    u32*   wi4pk= (u32*)(w + 136052736);            // 128*1024*4       =    524,288
    u32*   awpk = (u32*)(w + 136577024);            // 256*128*4        =    131,072
    uint4* wpkT = (uint4*)(w + 136708096);          // 2*14*1024*16     =    458,752
    float* S1   = (float*)(w + 33554432);           // 65536*128*4 = 32 MiB, aliases pre (dead)

    lstm_small<<<128, 512, 0, stream>>>(X, cw, cb, Wi1, Wh1, b1, Wi2, Wh2, b2, x12);
    cvt_all<<<2288, 256, 0, stream>>>(Wh3, Wh4, Wi3, Wi4, attW, wpk, wi3pk, wi4pk, awpk, wpkT);

    for (int c = 0; c < NCH; ++c) {
        int t0 = c * TC_;
        gemm128pk<0, 1><<<dim3(64, 8), 256, 0, stream>>>(x12, wi3pk, b3, pre, t0, 1024, 256);
        gemm128pk<0, 1><<<dim3(64, 8), 256, 0, stream>>>(x12, wi4pk, b4, pre + (size_t)MCH * 1024, t0, 1024, 256);
        lstm_big<<<128, 512, 0, stream>>>(pre, wpk, wpkT, state, enc, t0);
    }

    gemm128pk<1, 0><<<dim3(512, 1), 256, 0, stream>>>(enc, awpk, attWb, S1, 0, 128, 512);
    attn_head<<<64, 256, 0, stream>>>(S1, enc, attV, attVb, d1W, d1b, d2W, d2b, out);
}

// Round 12
// 2546.022 us; speedup vs baseline: 17.6990x; 1.3018x over previous
//
#include <hip/hip_runtime.h>
#include <hip/hip_fp16.h>

// Sizes fixed by the problem.
#define B_   64
#define T_   1024
#define H1_  128
#define H2_  256
#define TC_  128              // time-chunk for LSTM3/4 and (now) LSTM1/2
#define NCH  (T_ / TC_)       // 8 chunks
#define MCH  (B_ * TC_)       // 8192 rows per chunk per layer

typedef unsigned int  u32;
typedef unsigned short u16;
typedef _Float16 half2_t __attribute__((ext_vector_type(2)));

__device__ __forceinline__ float fdot2(u32 w, u32 h, float acc) {
    // v_dot2_f32_f16: acc += w.lo*h.lo + w.hi*h.hi (fp32 accumulate)
    return __builtin_amdgcn_fdot2(__builtin_bit_cast(half2_t, w),
                                  __builtin_bit_cast(half2_t, h), acc, false);
}
__device__ __forceinline__ u32 pk2(float a, float b) {
    __half2 h = __floats2half2_rn(a, b);
    return __builtin_bit_cast(u32, h);
}
__device__ __forceinline__ float hf(u16 u) { return __half2float(__builtin_bit_cast(__half, u)); }
__device__ __forceinline__ u16 fh(float f) { return __builtin_bit_cast(u16, __float2half(f)); }
__device__ __forceinline__ float sigf(float x) { return 1.0f / (1.0f + expf(-x)); }

// ---------------------------------------------------------------------------
// Weight conversions (packed fp16 pairs) + small-LSTM prologue precompute:
//  wpk  [2][128][1024]: Wh3/Wh4 pairs (k2, col j)
//  wi3pk[128][1024]:    Wi3 pairs
//  wi4pk[128][1024]:    Wi4 pairs with the feature-flip baked in
//  awpk [256][128]:     attW pairs
//  wpkT [2][14][1024]:  Wh3/Wh4 pairs k2=72..127 as lane-contiguous uint4
//  whs  [2][64][512]:   Wh1/Wh2 pairs
//  w4s  [2][4][512]:    conv-folded input taps per gate column
//  beffs[2][512]:       conv-folded bias per gate column
// ---------------------------------------------------------------------------
__global__ void cvt_all(const float* __restrict__ Wh3, const float* __restrict__ Wh4,
                        const float* __restrict__ Wi3, const float* __restrict__ Wi4,
                        const float* __restrict__ attW,
                        const float* __restrict__ Wh1, const float* __restrict__ Wh2,
                        const float* __restrict__ cw, const float* __restrict__ cb,
                        const float* __restrict__ Wi1, const float* __restrict__ Wi2,
                        const float* __restrict__ b1, const float* __restrict__ b2,
                        u32* __restrict__ wpk, u32* __restrict__ wi3pk,
                        u32* __restrict__ wi4pk, u32* __restrict__ awpk,
                        uint4* __restrict__ wpkT, u32* __restrict__ whs,
                        float* __restrict__ w4s, float* __restrict__ beffs)
{
    int idx = blockIdx.x * 256 + threadIdx.x;   // < 652288
    if (idx < 262144) {
        int l = idx >> 17, rem = idx & 131071, k2 = rem >> 10, j = rem & 1023;
        const float* W = l ? Wh4 : Wh3;
        wpk[idx] = pk2(W[(2 * k2) * 1024 + j], W[(2 * k2 + 1) * 1024 + j]);
    } else if (idx < 393216) {
        int rel = idx - 262144, k2 = rel >> 10, n = rel & 1023;
        wi3pk[rel] = pk2(Wi3[(2 * k2) * 1024 + n], Wi3[(2 * k2 + 1) * 1024 + n]);
    } else if (idx < 524288) {
        int rel = idx - 393216, k2 = rel >> 10, n = rel & 1023;
        wi4pk[rel] = pk2(Wi4[(255 - 2 * k2) * 1024 + n], Wi4[(254 - 2 * k2) * 1024 + n]);
    } else if (idx < 557056) {
        int rel = idx - 524288, k2 = rel >> 7, n = rel & 127;
        awpk[rel] = pk2(attW[(2 * k2) * 128 + n], attW[(2 * k2 + 1) * 128 + n]);
    } else if (idx < 585728) {
        int rel = idx - 557056;          // < 28672 = 2 * 14 * 1024
        int l = rel / 14336;
        int rem = rel - l * 14336;
        int q = rem >> 10, col = rem & 1023;
        const float* W = l ? Wh4 : Wh3;
        int k2 = 72 + 4 * q;
        uint4 v;
        v.x = pk2(W[(2 * k2 + 0) * 1024 + col], W[(2 * k2 + 1) * 1024 + col]);
        v.y = pk2(W[(2 * k2 + 2) * 1024 + col], W[(2 * k2 + 3) * 1024 + col]);
        v.z = pk2(W[(2 * k2 + 4) * 1024 + col], W[(2 * k2 + 5) * 1024 + col]);
        v.w = pk2(W[(2 * k2 + 6) * 1024 + col], W[(2 * k2 + 7) * 1024 + col]);
        wpkT[rel] = v;
    } else if (idx < 651264) {
        int rel = idx - 585728;          // < 65536 = 2 * 64 * 512
        int l = rel >> 15, rem = rel & 32767, p = rem >> 9, col = rem & 511;
        const float* W = l ? Wh2 : Wh1;
        whs[rel] = pk2(W[(2 * p) * 512 + col], W[(2 * p + 1) * 512 + col]);
    } else if (idx < 652288) {
        int rel = idx - 651264;          // < 1024
        int l = rel >> 9, col = rel & 511;
        const float* Wi = l ? Wi2 : Wi1;
        const float* bb = l ? b2 : b1;
#pragma unroll
        for (int kk = 0; kk < 4; ++kk) {
            float s = 0.f;
#pragma unroll
            for (int c0 = 0; c0 < 16; ++c0) {
                int cc = l ? (15 - c0) : c0;
                s += cw[kk * 16 + c0] * Wi[cc * 512 + col];
            }
            w4s[(l * 4 + kk) * 512 + col] = s;
        }
        float be = bb[col];
#pragma unroll
        for (int c0 = 0; c0 < 16; ++c0) {
            int cc = l ? (15 - c0) : c0;
            be += cb[c0] * Wi[cc * 512 + col];
        }
        beffs[l * 512 + col] = be;
    }
}

// ---------------------------------------------------------------------------
// FUSED persistent step: 256 blocks, 512 threads.
//  blocks   0..127: LSTM3/4 (big) chunk c-1  (skipped when c == 0)
//  blocks 128..255: LSTM1/2 (small) chunk c  (skipped when c == NCH)
// Small (90 us/chunk) hides under big (~240 us/chunk) — the two phases used
// only half the 256 CUs each when run serially (r11: 0.72 + 1.9 ms).
// Small state (c fp32, h fp16) persists via sstC/sstH — bit-identical to the
// monolithic run. Big is the r11-verified residency-split kernel.
// ---------------------------------------------------------------------------
__global__ __launch_bounds__(512) void fused_step(
    const u16* __restrict__ pre, const u32* __restrict__ wpk,
    const uint4* __restrict__ wpkT, float* __restrict__ state,
    u16* __restrict__ enc,
    const float* __restrict__ X, const u32* __restrict__ whs,
    const float* __restrict__ w4s, const float* __restrict__ beffs,
    float* __restrict__ sstC, u16* __restrict__ sstH,
    u16* __restrict__ x12, int c)
{
    __shared__ __align__(16) uint4 wlA[9][512];   // big: col j,     pairs 36..71
    __shared__ __align__(16) uint4 wlB[9][512];   // big: col 512+j, pairs 36..71
    __shared__ __align__(16) u32 hbuf_pk[128];    // big: 256 h packed fp16
    __shared__ float zbuf[1024];                  // big z / small z (first 512)
    __shared__ __align__(16) u32 hbs[64];         // small: 128 h packed fp16

    const int j = threadIdx.x;

    if (blockIdx.x < 128) {
        // ----------------------------- BIG ---------------------------------
        if (c == 0) return;
        const int t0 = (c - 1) * TC_;
        const int blk = blockIdx.x;
        const int b = blk >> 1;
        const int layer = blk & 1;

        const u32* wp = wpk + (size_t)layer * 131072;   // [k2][1024]
        u32 wrA[36], wrB[36];
#pragma unroll
        for (int q = 0; q < 36; ++q) {
            wrA[q] = wp[q * 1024 + j];
            wrB[q] = wp[q * 1024 + 512 + j];
        }
#pragma unroll
        for (int m = 0; m < 9; ++m) {
            uint4 va, vb;
            va.x = wp[(36 + 4 * m + 0) * 1024 + j];
            va.y = wp[(36 + 4 * m + 1) * 1024 + j];
            va.z = wp[(36 + 4 * m + 2) * 1024 + j];
            va.w = wp[(36 + 4 * m + 3) * 1024 + j];
            vb.x = wp[(36 + 4 * m + 0) * 1024 + 512 + j];
            vb.y = wp[(36 + 4 * m + 1) * 1024 + 512 + j];
            vb.z = wp[(36 + 4 * m + 2) * 1024 + 512 + j];
            vb.w = wp[(36 + 4 * m + 3) * 1024 + 512 + j];
            wlA[m][j] = va;
            wlB[m][j] = vb;
        }
        const uint4* wt = wpkT + (size_t)layer * 14 * 1024;

        float* st = state + ((size_t)layer * B_ + b) * 512;
        u16* hb16 = (u16*)hbuf_pk;
        float c_state = 0.f, h_last = 0.f;
        if (j < 256) {
            float h0 = (t0 == 0) ? 0.f : st[256 + j];
            c_state = (t0 == 0) ? 0.f : st[j];
            hb16[j] = fh(h0);
            h_last = h0;
        }
        __syncthreads();

        const u16* prow = pre + (size_t)(layer * MCH + b * TC_) * 1024;
        u16* encrow = enc + ((size_t)b * T_ + t0) * 512 + layer * 256;
        const uint4* hp4 = (const uint4*)hbuf_pk;

        for (int tt = 0; tt < TC_; ++tt, prow += 1024, encrow += 512) {
            u16 pA = prow[j], pB = prow[512 + j];
            float a0 = 0.f, a1 = 0.f, b0 = 0.f, b1 = 0.f;
#pragma unroll
            for (int m = 0; m < 9; ++m) {           // pairs 0..35 from VGPR
                uint4 hh = hp4[m];
                a0 = fdot2(wrA[4 * m + 0], hh.x, a0);
                a1 = fdot2(wrA[4 * m + 1], hh.y, a1);
                a0 = fdot2(wrA[4 * m + 2], hh.z, a0);
                a1 = fdot2(wrA[4 * m + 3], hh.w, a1);
                b0 = fdot2(wrB[4 * m + 0], hh.x, b0);
                b1 = fdot2(wrB[4 * m + 1], hh.y, b1);
                b0 = fdot2(wrB[4 * m + 2], hh.z, b0);
                b1 = fdot2(wrB[4 * m + 3], hh.w, b1);
            }
#pragma unroll
            for (int m = 0; m < 9; ++m) {           // pairs 36..71 from LDS
                uint4 hh = hp4[9 + m];
                uint4 wa = wlA[m][j];
                uint4 wb = wlB[m][j];
                a0 = fdot2(wa.x, hh.x, a0); a1 = fdot2(wa.y, hh.y, a1);
                a0 = fdot2(wa.z, hh.z, a0); a1 = fdot2(wa.w, hh.w, a1);
                b0 = fdot2(wb.x, hh.x, b0); b1 = fdot2(wb.y, hh.y, b1);
                b0 = fdot2(wb.z, hh.z, b0); b1 = fdot2(wb.w, hh.w, b1);
            }
#pragma unroll
            for (int q = 0; q < 14; ++q) {          // pairs 72..127 streamed (L2)
                uint4 hh = hp4[18 + q];
                uint4 wa = wt[q * 1024 + j];
                uint4 wb = wt[q * 1024 + 512 + j];
                a0 = fdot2(wa.x, hh.x, a0); a1 = fdot2(wa.y, hh.y, a1);
                a0 = fdot2(wa.z, hh.z, a0); a1 = fdot2(wa.w, hh.w, a1);
                b0 = fdot2(wb.x, hh.x, b0); b1 = fdot2(wb.y, hh.y, b1);
                b0 = fdot2(wb.z, hh.z, b0); b1 = fdot2(wb.w, hh.w, b1);
            }
            float zA = (a0 + a1) + hf(pA);          // col j: gate i or f
            float zB = (b0 + b1) + hf(pB);          // col 512+j: gate g or o
            zbuf[j] = sigf(zA);
            zbuf[512 + j] = (j < 256) ? tanhf(zB) : sigf(zB);
            __syncthreads();
            if (j < 256) {
                float gi = zbuf[j], gf = zbuf[256 + j], gg = zbuf[512 + j], go = zbuf[768 + j];
                c_state = gf * c_state + gi * gg;
                float h = go * tanhf(c_state);
                hb16[j] = fh(h);
                encrow[j] = fh(h);
                h_last = h;
            }
            __syncthreads();
        }
        if (j < 256) { st[j] = c_state; st[256 + j] = h_last; }
    } else {
        // ---------------------------- SMALL --------------------------------
        if (c >= NCH) return;
        const int chain = blockIdx.x - 128;
        const int b = chain >> 1;
        const int layer = chain & 1;

        float W4[4];
#pragma unroll
        for (int kk = 0; kk < 4; ++kk) W4[kk] = w4s[(layer * 4 + kk) * 512 + j];
        float beff = beffs[layer * 512 + j];
        u32 whp[64];
#pragma unroll
        for (int p = 0; p < 64; ++p) whp[p] = whs[(layer * 64 + p) * 512 + j];

        u16* hb16 = (u16*)hbs;
        float c_state = 0.f;
        if (j < 128) {
            if (c == 0) hb16[j] = 0;
            else { c_state = sstC[chain * 128 + j]; hb16[j] = sstH[chain * 128 + j]; }
        }
        const int t0 = c * TC_;
        const float* Xb = X + (size_t)b * T_;
        float xm1 = (t0 == 0) ? 0.f : Xb[t0 - 1];
        float x0 = Xb[t0], xp1 = Xb[t0 + 1], xp2 = Xb[t0 + 2];
        __syncthreads();

        const uint4* hp4 = (const uint4*)hbs;
        u16 hprev = 0;
        for (int t = t0; t < t0 + TC_; ++t) {
            float xnext = (t + 3 < T_) ? Xb[t + 3] : 0.f;

            float za = beff + xm1 * W4[0] + x0 * W4[1] + xp1 * W4[2] + xp2 * W4[3];
            float zb = 0.f, zc = 0.f, zd = 0.f;
#pragma unroll
            for (int m = 0; m < 16; ++m) {
                uint4 hh = hp4[m];
                za = fdot2(whp[4 * m + 0], hh.x, za);
                zb = fdot2(whp[4 * m + 1], hh.y, zb);
                zc = fdot2(whp[4 * m + 2], hh.z, zc);
                zd = fdot2(whp[4 * m + 3], hh.w, zd);
            }
            float z = (za + zb) + (zc + zd);
            // own-gate nonlinearity (wave-uniform branch): g-gate is [256,384)
            zbuf[j] = (j >= 256 && j < 384) ? tanhf(z) : sigf(z);
            __syncthreads();
            if (j < 128) {
                float gi = zbuf[j], gf = zbuf[128 + j], gg = zbuf[256 + j], go = zbuf[384 + j];
                c_state = gf * c_state + gi * gg;
                float h = go * tanhf(c_state);
                hprev = fh(h);
                hb16[j] = hprev;
                x12[((size_t)b * T_ + t) * 256 + layer * 128 + j] = hprev;
            }
            xm1 = x0; x0 = xp1; xp1 = xp2; xp2 = xnext;
            __syncthreads();
        }
        if (j < 128) { sstC[chain * 128 + j] = c_state; sstH[chain * 128 + j] = hprev; }
    }
}

// ---------------------------------------------------------------------------
// Merged per-chunk projection GEMM: grid (128, 8). Blocks 0..63 do Wi3 -> pre
// layer 0 rows, blocks 64..127 do Wi4 -> layer 1. Packed-fp16 fdot2 body.
// ---------------------------------------------------------------------------
__global__ __launch_bounds__(256) void gemm2(
    const u16* __restrict__ A, const u32* __restrict__ B3, const u32* __restrict__ B4,
    const float* __restrict__ b3, const float* __restrict__ b4,
    u16* __restrict__ pre, int t0)
{
    __shared__ __align__(16) u32 Apk[8][132];
    __shared__ __align__(16) u32 Bld[8][128];
    const int N = 1024, K = 256;
    const int tid = threadIdx.x;
    const int bx = blockIdx.x;
    const int layer = bx >> 6;
    const int m0 = (bx & 63) * 128;
    const int n0 = blockIdx.y * 128;
    const u32* Bpk = layer ? B4 : B3;
    const float* bias = layer ? b4 : b3;
    u16* outp = pre + (size_t)layer * MCH * 1024;

    const int tm = tid >> 4, tn = tid & 15;
    const int ar = tid >> 1, ap = (tid & 1) * 4;
    const int bkp = tid >> 5, bn4 = (tid & 31) * 4;

    int arow = m0 + ar;
    arow = (arow >> 7) * T_ + t0 + (arow & (TC_ - 1));

    float acc[8][8];
#pragma unroll
    for (int r = 0; r < 8; ++r)
#pragma unroll
        for (int c = 0; c < 8; ++c) acc[r][c] = 0.f;

    for (int k0 = 0; k0 < K; k0 += 16) {
        uint4 ua = *(const uint4*)(A + (size_t)arow * K + k0 + ap * 2);
        uint4 ub = *(const uint4*)(Bpk + (size_t)((k0 >> 1) + bkp) * N + n0 + bn4);
        Apk[ap + 0][ar] = ua.x; Apk[ap + 1][ar] = ua.y;
        Apk[ap + 2][ar] = ua.z; Apk[ap + 3][ar] = ua.w;
        *(uint4*)&Bld[bkp][bn4] = ub;
        __syncthreads();
#pragma unroll
        for (int kp = 0; kp < 8; ++kp) {
            u32 a[8], bp[8];
            *(uint4*)(a)      = *(const uint4*)&Apk[kp][tm * 8];
            *(uint4*)(a + 4)  = *(const uint4*)&Apk[kp][tm * 8 + 4];
            *(uint4*)(bp)     = *(const uint4*)&Bld[kp][tn * 8];
            *(uint4*)(bp + 4) = *(const uint4*)&Bld[kp][tn * 8 + 4];
#pragma unroll
            for (int r = 0; r < 8; ++r)
#pragma unroll
                for (int c = 0; c < 8; ++c)
                    acc[r][c] = fdot2(a[r], bp[c], acc[r][c]);
        }
        __syncthreads();
    }

    float bv[8];
#pragma unroll
    for (int c = 0; c < 8; ++c) bv[c] = bias[n0 + tn * 8 + c];
#pragma unroll
    for (int r = 0; r < 8; ++r) {
        u32 pkv[4];
#pragma unroll
        for (int c2 = 0; c2 < 4; ++c2)
            pkv[c2] = pk2(acc[r][2 * c2] + bv[2 * c2], acc[r][2 * c2 + 1] + bv[2 * c2 + 1]);
        uint4 st = make_uint4(pkv[0], pkv[1], pkv[2], pkv[3]);
        *(uint4*)(outp + (size_t)(m0 + tm * 8 + r) * N + n0 + tn * 8) = st;
    }
}

// ---------------------------------------------------------------------------
// S1 GEMM: enc[65536x512] @ attW[512x128] -> tanh fp32. Packed-fp16 B.
// ---------------------------------------------------------------------------
__global__ __launch_bounds__(256) void gemmS1(
    const u16* __restrict__ A, const u32* __restrict__ Bpk,
    const float* __restrict__ bias, float* __restrict__ outp)
{
    __shared__ __align__(16) u32 Apk[8][132];
    __shared__ __align__(16) u32 Bld[8][128];
    const int N = 128, K = 512;
    const int tid = threadIdx.x;
    const int m0 = blockIdx.x * 128;
    const int n0 = 0;
    const int tm = tid >> 4, tn = tid & 15;
    const int ar = tid >> 1, ap = (tid & 1) * 4;
    const int bkp = tid >> 5, bn4 = (tid & 31) * 4;
    const int arow = m0 + ar;

    float acc[8][8];
#pragma unroll
    for (int r = 0; r < 8; ++r)
#pragma unroll
        for (int c = 0; c < 8; ++c) acc[r][c] = 0.f;

    for (int k0 = 0; k0 < K; k0 += 16) {
        uint4 ua = *(const uint4*)(A + (size_t)arow * K + k0 + ap * 2);
        uint4 ub;
        if (bn4 < N) ub = *(const uint4*)(Bpk + (size_t)((k0 >> 1) + bkp) * N + n0 + bn4);
        else ub = make_uint4(0, 0, 0, 0);
        Apk[ap + 0][ar] = ua.x; Apk[ap + 1][ar] = ua.y;
        Apk[ap + 2][ar] = ua.z; Apk[ap + 3][ar] = ua.w;
        if (bn4 < N) *(uint4*)&Bld[bkp][bn4] = ub;
        __syncthreads();
#pragma unroll
        for (int kp = 0; kp < 8; ++kp) {
            u32 a[8], bp[8];
            *(uint4*)(a)      = *(const uint4*)&Apk[kp][tm * 8];
            *(uint4*)(a + 4)  = *(const uint4*)&Apk[kp][tm * 8 + 4];
            int cb = (tn & 7) * 8 + ((tn >> 3) & 1) * 64;   // wrap cols into 128
            cb = (tn * 8) & 127;
            *(uint4*)(bp)     = *(const uint4*)&Bld[kp][cb];
            *(uint4*)(bp + 4) = *(const uint4*)&Bld[kp][cb + 4];
#pragma unroll
            for (int r = 0; r < 8; ++r)
#pragma unroll
                for (int c = 0; c < 8; ++c)
                    acc[r][c] = fdot2(a[r], bp[c], acc[r][c]);
        }
        __syncthreads();
    }

    int ncol = (tn * 8) & 127;
    float bv[8];
#pragma unroll
    for (int c = 0; c < 8; ++c) bv[c] = bias[ncol + c];
    // two tn values map to each ncol; only tn < 16 with (tn*8)<128 are unique.
    if (tn < 16) {
#pragma unroll
        for (int r = 0; r < 8; ++r) {
            float v[8];
#pragma unroll
            for (int c = 0; c < 8; ++c) v[c] = tanhf(acc[r][c] + bv[c]);
            *(float4*)(outp + (size_t)(m0 + tm * 8 + r) * N + ncol)     = *(float4*)v;
            *(float4*)(outp + (size_t)(m0 + tm * 8 + r) * N + ncol + 4) = *(float4*)(v + 4);
        }
    }
}

// ---------------------------------------------------------------------------
// Attention pooling + head, one workgroup per batch.
// ---------------------------------------------------------------------------
__global__ __launch_bounds__(256) void attn_head(
    const float* __restrict__ S1, const u16* __restrict__ enc,
    const float* __restrict__ attV, const float* __restrict__ attVb,
    const float* __restrict__ d1W, const float* __restrict__ d1b,
    const float* __restrict__ d2W, const float* __restrict__ d2b,
    float* __restrict__ out)
{
    const int b = blockIdx.x;
    const int tid = threadIdx.x;
    const int lane = tid & 63, w = tid >> 6;

    __shared__ float sb[1024];
    __shared__ float red[32];
    __shared__ __align__(16) float ctx[512];
    __shared__ float h1s[128];

    float av0 = attV[lane], av1 = attV[64 + lane];
    const float* S1b = S1 + (size_t)b * T_ * 128;
    for (int it = 0; it < 256; ++it) {
        int t = it * 4 + w;
        const float* row = S1b + (size_t)t * 128;
        float p = row[lane] * av0 + row[64 + lane] * av1;
#pragma unroll
        for (int off = 32; off > 0; off >>= 1) p += __shfl_down(p, off);
        if (lane == 0) sb[t] = p + attVb[0];
    }
    __syncthreads();

    float mx = -3.0e38f;
#pragma unroll
    for (int q = 0; q < 4; ++q) mx = fmaxf(mx, sb[tid + 256 * q]);
#pragma unroll
    for (int off = 32; off > 0; off >>= 1) mx = fmaxf(mx, __shfl_down(mx, off));
    if (lane == 0) red[w] = mx;
    __syncthreads();
    if (tid == 0) red[8] = fmaxf(fmaxf(red[0], red[1]), fmaxf(red[2], red[3]));
    __syncthreads();
    float bm = red[8];
    float s = 0.f;
#pragma unroll
    for (int q = 0; q < 4; ++q) {
        float e = expf(sb[tid + 256 * q] - bm);
        sb[tid + 256 * q] = e;
        s += e;
    }
#pragma unroll
    for (int off = 32; off > 0; off >>= 1) s += __shfl_down(s, off);
    if (lane == 0) red[16 + w] = s;
    __syncthreads();
    if (tid == 0) red[24] = 1.0f / (red[16] + red[17] + red[18] + red[19]);
    __syncthreads();
    float inv = red[24];
#pragma unroll
    for (int q = 0; q < 4; ++q) sb[tid + 256 * q] *= inv;
    __syncthreads();

    const u16* encb = enc + (size_t)b * T_ * 512;
    float a0 = 0.f, a1 = 0.f;
    for (int t = 0; t < T_; ++t) {
        float wt = sb[t];
        a0 += wt * hf(encb[(size_t)t * 512 + tid]);
        a1 += wt * hf(encb[(size_t)t * 512 + 256 + tid]);
    }
    ctx[tid] = a0;
    ctx[256 + tid] = a1;
    __syncthreads();

    if (tid < 128) {
        float s1 = d1b[tid];
        for (int k = 0; k < 512; ++k) s1 += ctx[k] * d1W[k * 128 + tid];
        h1s[tid] = tanhf(s1);
    }
    __syncthreads();
    if (tid < 128) {
        float p = h1s[tid] * d2W[tid];
#pragma unroll
        for (int off = 32; off > 0; off >>= 1) p += __shfl_down(p, off);
        if ((tid & 63) == 0) red[28 + (tid >> 6)] = p;
    }
    __syncthreads();
    if (tid == 0) out[b] = red[28] + red[29] + d2b[0];
}

// ---------------------------------------------------------------------------
extern "C" void kernel_launch(void* const* d_in, const int* in_sizes, int n_in,
                              void* d_out, int out_size, void* d_ws, size_t ws_size,
                              hipStream_t stream)
{
    const float* X    = (const float*)d_in[0];
    const float* cw   = (const float*)d_in[1];
    const float* cb   = (const float*)d_in[2];
    const float* Wi1  = (const float*)d_in[3];
    const float* Wh1  = (const float*)d_in[4];
    const float* b1   = (const float*)d_in[5];
    const float* Wi2  = (const float*)d_in[6];
    const float* Wh2  = (const float*)d_in[7];
    const float* b2   = (const float*)d_in[8];
    const float* Wi3  = (const float*)d_in[9];
    const float* Wh3  = (const float*)d_in[10];
    const float* b3   = (const float*)d_in[11];
    const float* Wi4  = (const float*)d_in[12];
    const float* Wh4  = (const float*)d_in[13];
    const float* b4   = (const float*)d_in[14];
    const float* attW = (const float*)d_in[15];
    const float* attWb= (const float*)d_in[16];
    const float* attV = (const float*)d_in[17];
    const float* attVb= (const float*)d_in[18];
    const float* d1W  = (const float*)d_in[19];
    const float* d1b  = (const float*)d_in[20];
    const float* d2W  = (const float*)d_in[21];
    const float* d2b  = (const float*)d_in[22];
    float* out = (float*)d_out;

    // workspace layout (total 137,547,776 B ~ 131.2 MiB — under r2's proven 169 MB):
    char* w = (char*)d_ws;
    u16*   x12  = (u16*)w;                          // 33,554,432
    u16*   pre  = (u16*)(w + 33554432);             // 33,554,432 (per chunk, 2 layers)
    u16*   enc  = (u16*)(w + 67108864);             // 67,108,864
    u32*   wpk  = (u32*)(w + 134217728);            //  1,048,576
    float* state= (float*)(w + 135266304);          //    262,144
    u32*   wi3pk= (u32*)(w + 135528448);            //    524,288
    u32*   wi4pk= (u32*)(w + 136052736);            //    524,288
    u32*   awpk = (u32*)(w + 136577024);            //    131,072
    uint4* wpkT = (uint4*)(w + 136708096);          //    458,752
    u32*   whs  = (u32*)(w + 137166848);            //    262,144
    float* w4s  = (float*)(w + 137428992);          //     16,384
    float* beffs= (float*)(w + 137445376);          //      4,096
    float* sstC = (float*)(w + 137449472);          //     65,536
    u16*   sstH = (u16*)(w + 137515008);            //     32,768
    float* S1   = (float*)(w + 33554432);           // 32 MiB, aliases pre (dead after chunks)

    cvt_all<<<2548, 256, 0, stream>>>(Wh3, Wh4, Wi3, Wi4, attW, Wh1, Wh2, cw, cb,
                                      Wi1, Wi2, b1, b2,
                                      wpk, wi3pk, wi4pk, awpk, wpkT, whs, w4s, beffs);

    for (int c = 0; c <= NCH; ++c) {
        fused_step<<<256, 512, 0, stream>>>(pre, wpk, wpkT, state, enc,
                                            X, whs, w4s, beffs, sstC, sstH, x12, c);
        if (c < NCH)
            gemm2<<<dim3(128, 8), 256, 0, stream>>>(x12, wi3pk, wi4pk, b3, b4, pre, c * TC_);
    }

    gemmS1<<<512, 256, 0, stream>>>(enc, awpk, attWb, S1);
    attn_head<<<64, 256, 0, stream>>>(S1, enc, attV, attVb, d1W, d1b, d2W, d2b, out);
}

// Round 13
// 2108.539 us; speedup vs baseline: 21.3712x; 1.2075x over previous
//
#include <hip/hip_runtime.h>
#include <hip/hip_fp16.h>

// Sizes fixed by the problem.
#define B_   64
#define T_   1024
#define H1_  128
#define H2_  256
#define TC_  128              // time-chunk for LSTM3/4 and LSTM1/2
#define NCH  (T_ / TC_)       // 8 chunks
#define MCH  (B_ * TC_)       // 8192 rows per chunk per layer

typedef unsigned int  u32;
typedef unsigned short u16;
typedef _Float16 half2_t __attribute__((ext_vector_type(2)));
typedef _Float16 half8 __attribute__((ext_vector_type(8)));
typedef float f32x4 __attribute__((ext_vector_type(4)));

__device__ __forceinline__ float fdot2(u32 w, u32 h, float acc) {
    return __builtin_amdgcn_fdot2(__builtin_bit_cast(half2_t, w),
                                  __builtin_bit_cast(half2_t, h), acc, false);
}
__device__ __forceinline__ u32 pk2(float a, float b) {
    __half2 h = __floats2half2_rn(a, b);
    return __builtin_bit_cast(u32, h);
}
__device__ __forceinline__ float hf(u16 u) { return __half2float(__builtin_bit_cast(__half, u)); }
__device__ __forceinline__ u16 fh(float f) { return __builtin_bit_cast(u16, __float2half(f)); }
__device__ __forceinline__ float sigf(float x) { return 1.0f / (1.0f + expf(-x)); }

// ---------------------------------------------------------------------------
// Weight conversions (packed fp16 pairs) + small-LSTM prologue precompute:
//  wpk  [2][128][1024]: Wh3/Wh4 pairs (k2, col j)            (fused big)
//  wi3T [1024][128]:    Wi3 pairs, N-major (for MFMA B staging)
//  wi4T [1024][128]:    Wi4 pairs, N-major, feature-flip baked in
//  awT  [128][256]:     attW pairs, N-major
//  wpkT [2][14][1024]:  Wh3/Wh4 pairs k2=72..127 lane-contiguous (fused stream)
//  whs  [2][64][512]:   Wh1/Wh2 pairs
//  w4s, beffs:          conv-folded taps/bias
// ---------------------------------------------------------------------------
__global__ void cvt_all(const float* __restrict__ Wh3, const float* __restrict__ Wh4,
                        const float* __restrict__ Wi3, const float* __restrict__ Wi4,
                        const float* __restrict__ attW,
                        const float* __restrict__ Wh1, const float* __restrict__ Wh2,
                        const float* __restrict__ cw, const float* __restrict__ cb,
                        const float* __restrict__ Wi1, const float* __restrict__ Wi2,
                        const float* __restrict__ b1, const float* __restrict__ b2,
                        u32* __restrict__ wpk, u32* __restrict__ wi3T,
                        u32* __restrict__ wi4T, u32* __restrict__ awT,
                        uint4* __restrict__ wpkT, u32* __restrict__ whs,
                        float* __restrict__ w4s, float* __restrict__ beffs)
{
    int idx = blockIdx.x * 256 + threadIdx.x;   // < 652288
    if (idx < 262144) {
        int l = idx >> 17, rem = idx & 131071, k2 = rem >> 10, j = rem & 1023;
        const float* W = l ? Wh4 : Wh3;
        wpk[idx] = pk2(W[(2 * k2) * 1024 + j], W[(2 * k2 + 1) * 1024 + j]);
    } else if (idx < 393216) {
        int rel = idx - 262144, n = rel >> 7, kp = rel & 127;   // [n][kp]
        wi3T[rel] = pk2(Wi3[(2 * kp) * 1024 + n], Wi3[(2 * kp + 1) * 1024 + n]);
    } else if (idx < 524288) {
        int rel = idx - 393216, n = rel >> 7, kp = rel & 127;   // [n][kp], flip
        wi4T[rel] = pk2(Wi4[(255 - 2 * kp) * 1024 + n], Wi4[(254 - 2 * kp) * 1024 + n]);
    } else if (idx < 557056) {
        int rel = idx - 524288, n = rel >> 8, kp = rel & 255;   // [n][kp]
        awT[rel] = pk2(attW[(2 * kp) * 128 + n], attW[(2 * kp + 1) * 128 + n]);
    } else if (idx < 585728) {
        int rel = idx - 557056;          // < 28672 = 2 * 14 * 1024
        int l = rel / 14336;
        int rem = rel - l * 14336;
        int q = rem >> 10, col = rem & 1023;
        const float* W = l ? Wh4 : Wh3;
        int k2 = 72 + 4 * q;
        uint4 v;
        v.x = pk2(W[(2 * k2 + 0) * 1024 + col], W[(2 * k2 + 1) * 1024 + col]);
        v.y = pk2(W[(2 * k2 + 2) * 1024 + col], W[(2 * k2 + 3) * 1024 + col]);
        v.z = pk2(W[(2 * k2 + 4) * 1024 + col], W[(2 * k2 + 5) * 1024 + col]);
        v.w = pk2(W[(2 * k2 + 6) * 1024 + col], W[(2 * k2 + 7) * 1024 + col]);
        wpkT[rel] = v;
    } else if (idx < 651264) {
        int rel = idx - 585728;          // < 65536 = 2 * 64 * 512
        int l = rel >> 15, rem = rel & 32767, p = rem >> 9, col = rem & 511;
        const float* W = l ? Wh2 : Wh1;
        whs[rel] = pk2(W[(2 * p) * 512 + col], W[(2 * p + 1) * 512 + col]);
    } else if (idx < 652288) {
        int rel = idx - 651264;          // < 1024
        int l = rel >> 9, col = rel & 511;
        const float* Wi = l ? Wi2 : Wi1;
        const float* bb = l ? b2 : b1;
#pragma unroll
        for (int kk = 0; kk < 4; ++kk) {
            float s = 0.f;
#pragma unroll
            for (int c0 = 0; c0 < 16; ++c0) {
                int cc = l ? (15 - c0) : c0;
                s += cw[kk * 16 + c0] * Wi[cc * 512 + col];
            }
            w4s[(l * 4 + kk) * 512 + col] = s;
        }
        float be = bb[col];
#pragma unroll
        for (int c0 = 0; c0 < 16; ++c0) {
            int cc = l ? (15 - c0) : c0;
            be += cb[c0] * Wi[cc * 512 + col];
        }
        beffs[l * 512 + col] = be;
    }
}

// ---------------------------------------------------------------------------
// FUSED persistent step: 256 blocks, 512 threads. (unchanged from r12 — at
// its streaming floor: 56 streamed pairs/col = 229 KB/step @ ~64 B/cy/CU)
//  blocks   0..127: LSTM3/4 (big) chunk c-1  (skipped when c == 0)
//  blocks 128..255: LSTM1/2 (small) chunk c  (skipped when c == NCH)
// ---------------------------------------------------------------------------
__global__ __launch_bounds__(512) void fused_step(
    const u16* __restrict__ pre, const u32* __restrict__ wpk,
    const uint4* __restrict__ wpkT, float* __restrict__ state,
    u16* __restrict__ enc,
    const float* __restrict__ X, const u32* __restrict__ whs,
    const float* __restrict__ w4s, const float* __restrict__ beffs,
    float* __restrict__ sstC, u16* __restrict__ sstH,
    u16* __restrict__ x12, int c)
{
    __shared__ __align__(16) uint4 wlA[9][512];
    __shared__ __align__(16) uint4 wlB[9][512];
    __shared__ __align__(16) u32 hbuf_pk[128];
    __shared__ float zbuf[1024];
    __shared__ __align__(16) u32 hbs[64];

    const int j = threadIdx.x;

    if (blockIdx.x < 128) {
        // ----------------------------- BIG ---------------------------------
        if (c == 0) return;
        const int t0 = (c - 1) * TC_;
        const int blk = blockIdx.x;
        const int b = blk >> 1;
        const int layer = blk & 1;

        const u32* wp = wpk + (size_t)layer * 131072;
        u32 wrA[36], wrB[36];
#pragma unroll
        for (int q = 0; q < 36; ++q) {
            wrA[q] = wp[q * 1024 + j];
            wrB[q] = wp[q * 1024 + 512 + j];
        }
#pragma unroll
        for (int m = 0; m < 9; ++m) {
            uint4 va, vb;
            va.x = wp[(36 + 4 * m + 0) * 1024 + j];
            va.y = wp[(36 + 4 * m + 1) * 1024 + j];
            va.z = wp[(36 + 4 * m + 2) * 1024 + j];
            va.w = wp[(36 + 4 * m + 3) * 1024 + j];
            vb.x = wp[(36 + 4 * m + 0) * 1024 + 512 + j];
            vb.y = wp[(36 + 4 * m + 1) * 1024 + 512 + j];
            vb.z = wp[(36 + 4 * m + 2) * 1024 + 512 + j];
            vb.w = wp[(36 + 4 * m + 3) * 1024 + 512 + j];
            wlA[m][j] = va;
            wlB[m][j] = vb;
        }
        const uint4* wt = wpkT + (size_t)layer * 14 * 1024;

        float* st = state + ((size_t)layer * B_ + b) * 512;
        u16* hb16 = (u16*)hbuf_pk;
        float c_state = 0.f, h_last = 0.f;
        if (j < 256) {
            float h0 = (t0 == 0) ? 0.f : st[256 + j];
            c_state = (t0 == 0) ? 0.f : st[j];
            hb16[j] = fh(h0);
            h_last = h0;
        }
        __syncthreads();

        const u16* prow = pre + (size_t)(layer * MCH + b * TC_) * 1024;
        u16* encrow = enc + ((size_t)b * T_ + t0) * 512 + layer * 256;
        const uint4* hp4 = (const uint4*)hbuf_pk;

        for (int tt = 0; tt < TC_; ++tt, prow += 1024, encrow += 512) {
            u16 pA = prow[j], pB = prow[512 + j];
            float a0 = 0.f, a1 = 0.f, b0 = 0.f, b1 = 0.f;
#pragma unroll
            for (int m = 0; m < 9; ++m) {
                uint4 hh = hp4[m];
                a0 = fdot2(wrA[4 * m + 0], hh.x, a0);
                a1 = fdot2(wrA[4 * m + 1], hh.y, a1);
                a0 = fdot2(wrA[4 * m + 2], hh.z, a0);
                a1 = fdot2(wrA[4 * m + 3], hh.w, a1);
                b0 = fdot2(wrB[4 * m + 0], hh.x, b0);
                b1 = fdot2(wrB[4 * m + 1], hh.y, b1);
                b0 = fdot2(wrB[4 * m + 2], hh.z, b0);
                b1 = fdot2(wrB[4 * m + 3], hh.w, b1);
            }
#pragma unroll
            for (int m = 0; m < 9; ++m) {
                uint4 hh = hp4[9 + m];
                uint4 wa = wlA[m][j];
                uint4 wb = wlB[m][j];
                a0 = fdot2(wa.x, hh.x, a0); a1 = fdot2(wa.y, hh.y, a1);
                a0 = fdot2(wa.z, hh.z, a0); a1 = fdot2(wa.w, hh.w, a1);
                b0 = fdot2(wb.x, hh.x, b0); b1 = fdot2(wb.y, hh.y, b1);
                b0 = fdot2(wb.z, hh.z, b0); b1 = fdot2(wb.w, hh.w, b1);
            }
#pragma unroll
            for (int q = 0; q < 14; ++q) {
                uint4 hh = hp4[18 + q];
                uint4 wa = wt[q * 1024 + j];
                uint4 wb = wt[q * 1024 + 512 + j];
                a0 = fdot2(wa.x, hh.x, a0); a1 = fdot2(wa.y, hh.y, a1);
                a0 = fdot2(wa.z, hh.z, a0); a1 = fdot2(wa.w, hh.w, a1);
                b0 = fdot2(wb.x, hh.x, b0); b1 = fdot2(wb.y, hh.y, b1);
                b0 = fdot2(wb.z, hh.z, b0); b1 = fdot2(wb.w, hh.w, b1);
            }
            float zA = (a0 + a1) + hf(pA);
            float zB = (b0 + b1) + hf(pB);
            zbuf[j] = sigf(zA);
            zbuf[512 + j] = (j < 256) ? tanhf(zB) : sigf(zB);
            __syncthreads();
            if (j < 256) {
                float gi = zbuf[j], gf = zbuf[256 + j], gg = zbuf[512 + j], go = zbuf[768 + j];
                c_state = gf * c_state + gi * gg;
                float h = go * tanhf(c_state);
                hb16[j] = fh(h);
                encrow[j] = fh(h);
                h_last = h;
            }
            __syncthreads();
        }
        if (j < 256) { st[j] = c_state; st[256 + j] = h_last; }
    } else {
        // ---------------------------- SMALL --------------------------------
        if (c >= NCH) return;
        const int chain = blockIdx.x - 128;
        const int b = chain >> 1;
        const int layer = chain & 1;

        float W4[4];
#pragma unroll
        for (int kk = 0; kk < 4; ++kk) W4[kk] = w4s[(layer * 4 + kk) * 512 + j];
        float beff = beffs[layer * 512 + j];
        u32 whp[64];
#pragma unroll
        for (int p = 0; p < 64; ++p) whp[p] = whs[(layer * 64 + p) * 512 + j];

        u16* hb16 = (u16*)hbs;
        float c_state = 0.f;
        if (j < 128) {
            if (c == 0) hb16[j] = 0;
            else { c_state = sstC[chain * 128 + j]; hb16[j] = sstH[chain * 128 + j]; }
        }
        const int t0 = c * TC_;
        const float* Xb = X + (size_t)b * T_;
        float xm1 = (t0 == 0) ? 0.f : Xb[t0 - 1];
        float x0 = Xb[t0], xp1 = Xb[t0 + 1], xp2 = Xb[t0 + 2];
        __syncthreads();

        const uint4* hp4 = (const uint4*)hbs;
        u16 hprev = 0;
        for (int t = t0; t < t0 + TC_; ++t) {
            float xnext = (t + 3 < T_) ? Xb[t + 3] : 0.f;

            float za = beff + xm1 * W4[0] + x0 * W4[1] + xp1 * W4[2] + xp2 * W4[3];
            float zb = 0.f, zc = 0.f, zd = 0.f;
#pragma unroll
            for (int m = 0; m < 16; ++m) {
                uint4 hh = hp4[m];
                za = fdot2(whp[4 * m + 0], hh.x, za);
                zb = fdot2(whp[4 * m + 1], hh.y, zb);
                zc = fdot2(whp[4 * m + 2], hh.z, zc);
                zd = fdot2(whp[4 * m + 3], hh.w, zd);
            }
            float z = (za + zb) + (zc + zd);
            zbuf[j] = (j >= 256 && j < 384) ? tanhf(z) : sigf(z);
            __syncthreads();
            if (j < 128) {
                float gi = zbuf[j], gf = zbuf[128 + j], gg = zbuf[256 + j], go = zbuf[384 + j];
                c_state = gf * c_state + gi * gg;
                float h = go * tanhf(c_state);
                hprev = fh(h);
                hb16[j] = hprev;
                x12[((size_t)b * T_ + t) * 256 + layer * 128 + j] = hprev;
            }
            xm1 = x0; x0 = xp1; xp1 = xp2; xp2 = xnext;
            __syncthreads();
        }
        if (j < 128) { sstC[chain * 128 + j] = c_state; sstH[chain * 128 + j] = hprev; }
    }
}

// ---------------------------------------------------------------------------
// MFMA fp16 GEMM: BM=BN=128, BK=32, 256 thr = 4 waves, 64x64 per wave,
// v_mfma_f32_16x16x32_f16. Operand layout (gfx950 = two stacked 16-K halves,
// each CDNA3-style): lane l elems {0..3} = M[l&15][4*(l>>4)+e], elems {4..7} =
// M[l&15][16+4*(l>>4)+e]; D: col=l&15, row=4*(l>>4)+i (m89-verified).
// A: fp16 row-major [M][K] (CHUNK: row remap). B: pair-transposed u32 [N][K/2].
// LAYERED: grid.x=128, bx>>6 selects (B0,bias0,out)+layer offset.
// OUTMODE 0: fp16 acc+bias -> out.  OUTMODE 1: fp32 tanh(acc+bias) -> out.
// ---------------------------------------------------------------------------
template<int OUTMODE, int CHUNK, int LAYERED>
__global__ __launch_bounds__(256) void gemm_mfma(
    const u16* __restrict__ A, const u32* __restrict__ B0, const u32* __restrict__ B1,
    const float* __restrict__ bias0, const float* __restrict__ bias1,
    void* __restrict__ outv, int t0, int N, int K)
{
    __shared__ __align__(16) u32 Al[128][20];   // [row][16 u32 k + 4 pad]
    __shared__ __align__(16) u32 Bl[128][20];   // [col][16 u32 k + 4 pad]
    const int tid = threadIdx.x;
    const int bx = blockIdx.x;
    const int layer = LAYERED ? (bx >> 6) : 0;
    const int m0 = LAYERED ? ((bx & 63) * 128) : (bx * 128);
    const int n0 = blockIdx.y * 128;
    const u32* Bpk = layer ? B1 : B0;
    const float* bias = layer ? bias1 : bias0;
    const int K2 = K >> 1;

    const int w = tid >> 6;
    const int lane = tid & 63;
    const int wr = (w >> 1) * 64, wc = (w & 1) * 64;
    const int lr = lane & 15, lg = lane >> 4;

    f32x4 acc[4][4];
#pragma unroll
    for (int r = 0; r < 4; ++r)
#pragma unroll
        for (int c = 0; c < 4; ++c) acc[r][c] = (f32x4){0.f, 0.f, 0.f, 0.f};

    for (int k0 = 0; k0 < K; k0 += 32) {
        const int kp0 = k0 >> 1;
#pragma unroll
        for (int it = 0; it < 2; ++it) {
            int idx = tid + it * 256;
            int row = idx >> 2, q = idx & 3;
            int grow = m0 + row;
            size_t garow = CHUNK ? ((size_t)(grow >> 7) * T_ + t0 + (grow & 127)) : (size_t)grow;
            uint4 ua = *(const uint4*)(A + garow * K + k0 + q * 8);
            *(uint4*)&Al[row][q * 4] = ua;
            uint4 ub = *(const uint4*)(Bpk + (size_t)(n0 + row) * K2 + kp0 + q * 4);
            *(uint4*)&Bl[row][q * 4] = ub;
        }
        __syncthreads();
        // B fragments (4): two b64 reads each (k-chunks 4*lg and 16+4*lg)
        half8 bfr[4];
#pragma unroll
        for (int c = 0; c < 4; ++c) {
            const u32* bp = &Bl[wc + c * 16 + lr][0];
            uint2 blo = *(const uint2*)(bp + 2 * lg);
            uint2 bhi = *(const uint2*)(bp + 8 + 2 * lg);
            uint4 bf = make_uint4(blo.x, blo.y, bhi.x, bhi.y);
            bfr[c] = __builtin_bit_cast(half8, bf);
        }
#pragma unroll
        for (int r = 0; r < 4; ++r) {
            const u32* ap = &Al[wr + r * 16 + lr][0];
            uint2 alo = *(const uint2*)(ap + 2 * lg);
            uint2 ahi = *(const uint2*)(ap + 8 + 2 * lg);
            uint4 af = make_uint4(alo.x, alo.y, ahi.x, ahi.y);
            half8 av = __builtin_bit_cast(half8, af);
#pragma unroll
            for (int c = 0; c < 4; ++c)
                acc[r][c] = __builtin_amdgcn_mfma_f32_16x16x32_f16(av, bfr[c], acc[r][c], 0, 0, 0);
        }
        __syncthreads();
    }

    if (OUTMODE == 0) {
        u16* outp = (u16*)outv + (LAYERED ? (size_t)layer * MCH * 1024 : 0);
#pragma unroll
        for (int c = 0; c < 4; ++c) {
            int col = n0 + wc + c * 16 + lr;
            float bvs = bias[col];
#pragma unroll
            for (int r = 0; r < 4; ++r) {
                int orow = m0 + wr + r * 16 + 4 * lg;
#pragma unroll
                for (int i = 0; i < 4; ++i)
                    outp[(size_t)(orow + i) * N + col] = fh(acc[r][c][i] + bvs);
            }
        }
    } else {
        float* outp = (float*)outv;
#pragma unroll
        for (int c = 0; c < 4; ++c) {
            int col = n0 + wc + c * 16 + lr;
            float bvs = bias[col];
#pragma unroll
            for (int r = 0; r < 4; ++r) {
                int orow = m0 + wr + r * 16 + 4 * lg;
#pragma unroll
                for (int i = 0; i < 4; ++i)
                    outp[(size_t)(orow + i) * N + col] = tanhf(acc[r][c][i] + bvs);
            }
        }
    }
}

// ---------------------------------------------------------------------------
// Attention pooling + head, one workgroup per batch. (unchanged)
// ---------------------------------------------------------------------------
__global__ __launch_bounds__(256) void attn_head(
    const float* __restrict__ S1, const u16* __restrict__ enc,
    const float* __restrict__ attV, const float* __restrict__ attVb,
    const float* __restrict__ d1W, const float* __restrict__ d1b,
    const float* __restrict__ d2W, const float* __restrict__ d2b,
    float* __restrict__ out)
{
    const int b = blockIdx.x;
    const int tid = threadIdx.x;
    const int lane = tid & 63, w = tid >> 6;

    __shared__ float sb[1024];
    __shared__ float red[32];
    __shared__ __align__(16) float ctx[512];
    __shared__ float h1s[128];

    float av0 = attV[lane], av1 = attV[64 + lane];
    const float* S1b = S1 + (size_t)b * T_ * 128;
    for (int it = 0; it < 256; ++it) {
        int t = it * 4 + w;
        const float* row = S1b + (size_t)t * 128;
        float p = row[lane] * av0 + row[64 + lane] * av1;
#pragma unroll
        for (int off = 32; off > 0; off >>= 1) p += __shfl_down(p, off);
        if (lane == 0) sb[t] = p + attVb[0];
    }
    __syncthreads();

    float mx = -3.0e38f;
#pragma unroll
    for (int q = 0; q < 4; ++q) mx = fmaxf(mx, sb[tid + 256 * q]);
#pragma unroll
    for (int off = 32; off > 0; off >>= 1) mx = fmaxf(mx, __shfl_down(mx, off));
    if (lane == 0) red[w] = mx;
    __syncthreads();
    if (tid == 0) red[8] = fmaxf(fmaxf(red[0], red[1]), fmaxf(red[2], red[3]));
    __syncthreads();
    float bm = red[8];
    float s = 0.f;
#pragma unroll
    for (int q = 0; q < 4; ++q) {
        float e = expf(sb[tid + 256 * q] - bm);
        sb[tid + 256 * q] = e;
        s += e;
    }
#pragma unroll
    for (int off = 32; off > 0; off >>= 1) s += __shfl_down(s, off);
    if (lane == 0) red[16 + w] = s;
    __syncthreads();
    if (tid == 0) red[24] = 1.0f / (red[16] + red[17] + red[18] + red[19]);
    __syncthreads();
    float inv = red[24];
#pragma unroll
    for (int q = 0; q < 4; ++q) sb[tid + 256 * q] *= inv;
    __syncthreads();

    const u16* encb = enc + (size_t)b * T_ * 512;
    float a0 = 0.f, a1 = 0.f;
    for (int t = 0; t < T_; ++t) {
        float wt = sb[t];
        a0 += wt * hf(encb[(size_t)t * 512 + tid]);
        a1 += wt * hf(encb[(size_t)t * 512 + 256 + tid]);
    }
    ctx[tid] = a0;
    ctx[256 + tid] = a1;
    __syncthreads();

    if (tid < 128) {
        float s1 = d1b[tid];
        for (int k = 0; k < 512; ++k) s1 += ctx[k] * d1W[k * 128 + tid];
        h1s[tid] = tanhf(s1);
    }
    __syncthreads();
    if (tid < 128) {
        float p = h1s[tid] * d2W[tid];
#pragma unroll
        for (int off = 32; off > 0; off >>= 1) p += __shfl_down(p, off);
        if ((tid & 63) == 0) red[28 + (tid >> 6)] = p;
    }
    __syncthreads();
    if (tid == 0) out[b] = red[28] + red[29] + d2b[0];
}

// ---------------------------------------------------------------------------
extern "C" void kernel_launch(void* const* d_in, const int* in_sizes, int n_in,
                              void* d_out, int out_size, void* d_ws, size_t ws_size,
                              hipStream_t stream)
{
    const float* X    = (const float*)d_in[0];
    const float* cw   = (const float*)d_in[1];
    const float* cb   = (const float*)d_in[2];
    const float* Wi1  = (const float*)d_in[3];
    const float* Wh1  = (const float*)d_in[4];
    const float* b1   = (const float*)d_in[5];
    const float* Wi2  = (const float*)d_in[6];
    const float* Wh2  = (const float*)d_in[7];
    const float* b2   = (const float*)d_in[8];
    const float* Wi3  = (const float*)d_in[9];
    const float* Wh3  = (const float*)d_in[10];
    const float* b3   = (const float*)d_in[11];
    const float* Wi4  = (const float*)d_in[12];
    const float* Wh4  = (const float*)d_in[13];
    const float* b4   = (const float*)d_in[14];
    const float* attW = (const float*)d_in[15];
    const float* attWb= (const float*)d_in[16];
    const float* attV = (const float*)d_in[17];
    const float* attVb= (const float*)d_in[18];
    const float* d1W  = (const float*)d_in[19];
    const float* d1b  = (const float*)d_in[20];
    const float* d2W  = (const float*)d_in[21];
    const float* d2b  = (const float*)d_in[22];
    float* out = (float*)d_out;

    // workspace layout (total 137,547,776 B ~ 131.2 MiB — under r2's proven 169 MB):
    char* w = (char*)d_ws;
    u16*   x12  = (u16*)w;                          // 33,554,432
    u16*   pre  = (u16*)(w + 33554432);             // 33,554,432 (per chunk, 2 layers)
    u16*   enc  = (u16*)(w + 67108864);             // 67,108,864
    u32*   wpk  = (u32*)(w + 134217728);            //  1,048,576
    float* state= (float*)(w + 135266304);          //    262,144
    u32*   wi3T = (u32*)(w + 135528448);            //    524,288
    u32*   wi4T = (u32*)(w + 136052736);            //    524,288
    u32*   awT  = (u32*)(w + 136577024);            //    131,072
    uint4* wpkT = (uint4*)(w + 136708096);          //    458,752
    u32*   whs  = (u32*)(w + 137166848);            //    262,144
    float* w4s  = (float*)(w + 137428992);          //     16,384
    float* beffs= (float*)(w + 137445376);          //      4,096
    float* sstC = (float*)(w + 137449472);          //     65,536
    u16*   sstH = (u16*)(w + 137515008);            //     32,768
    float* S1   = (float*)(w + 33554432);           // 32 MiB, aliases pre (dead after chunks)

    cvt_all<<<2548, 256, 0, stream>>>(Wh3, Wh4, Wi3, Wi4, attW, Wh1, Wh2, cw, cb,
                                      Wi1, Wi2, b1, b2,
                                      wpk, wi3T, wi4T, awT, wpkT, whs, w4s, beffs);

    for (int c = 0; c <= NCH; ++c) {
        fused_step<<<256, 512, 0, stream>>>(pre, wpk, wpkT, state, enc,
                                            X, whs, w4s, beffs, sstC, sstH, x12, c);
        if (c < NCH)
            gemm_mfma<0, 1, 1><<<dim3(128, 8), 256, 0, stream>>>(
                x12, wi3T, wi4T, b3, b4, pre, c * TC_, 1024, 256);
    }

    gemm_mfma<1, 0, 0><<<dim3(512, 1), 256, 0, stream>>>(
        enc, awT, awT, attWb, attWb, S1, 0, 128, 512);
    attn_head<<<64, 256, 0, stream>>>(S1, enc, attV, attVb, d1W, d1b, d2W, d2b, out);
}